// Round 2
// baseline (398.115 us; speedup 1.0000x reference)
//
#include <hip/hip_runtime.h>
#include <math.h>

constexpr int NN   = 50000;   // nodes
constexpr int NE   = 400000;  // edges
constexpr int INC  = 128;     // in channels
constexpr int NH   = 4;       // heads
constexpr int D1   = 256;     // NH*HIDC
constexpr int D4   = 1024;    // 4*D1 fused QKVS logical cols
constexpr int NOUT = 10;      // classes
constexpr int NG   = 64;      // graphs
constexpr int NB_SCAN = (NN + 255) / 256;   // 196 scan blocks

// GEMM output split per node:
//   QS[node][512] bf16 : cols 0..255 = Q, cols 256..511 = S
//   KV8[node][512] fp8 : byte j -> group g=j>>3, off=j&7: off<4 -> K ch 4g+off,
//                                                        off>=4 -> V ch 4g+(off-4)
// Lane t of node_attn reads 8 B at node*512 + t*8 = [K c0..c0+3 | V c0..c0+3].

typedef __attribute__((ext_vector_type(8))) short bf16x8;   // MFMA A/B frag
typedef __attribute__((ext_vector_type(4))) float f32x4;    // MFMA C/D frag
typedef __attribute__((ext_vector_type(2))) float f32x2;

// ---------- bf16 helpers ----------
__device__ __forceinline__ short f2b(float f) {
  union { float f; unsigned int i; } v; v.f = f;
  unsigned int x = v.i;
  return (short)((x + 0x7FFFu + ((x >> 16) & 1u)) >> 16);
}
__device__ __forceinline__ float b2f(short u) {
  union { unsigned int i; float f; } v; v.i = ((unsigned int)(unsigned short)u) << 16;
  return v.f;
}
__device__ __forceinline__ float4 ld4b(const short* p) {
  short4 u = *(const short4*)p;
  return make_float4(b2f(u.x), b2f(u.y), b2f(u.z), b2f(u.w));
}
// pack 4 floats -> 4 fp8 e4m3 bytes (HW convert)
__device__ __forceinline__ int pk_fp8x4(float a, float b, float c, float d) {
  int v = __builtin_amdgcn_cvt_pk_fp8_f32(a, b, 0, false);
  v = __builtin_amdgcn_cvt_pk_fp8_f32(c, d, v, true);
  return v;
}

// ---------- async global->LDS 16B ----------
__device__ __forceinline__ void gld_lds16(const short* g, short* l) {
  __builtin_amdgcn_global_load_lds(
      (const __attribute__((address_space(1))) unsigned int*)g,
      (__attribute__((address_space(3))) unsigned int*)l, 16, 0, 0);
}

// ---------- fused converts + zeroing (one dispatch) ----------
constexpr int CVT_XB  = (NN * INC / 4 + 255) / 256;   // 6250 blocks
constexpr int CVT_W1B = (4 * D1 * INC + 255) / 256;   // 512
constexpr int CVT_W2B = (4 * D1 * D1 + 255) / 256;    // 1024
constexpr int CVT_BB  = 8;                            // bias blocks
constexpr int CVT_DB  = (NN + 255) / 256;             // deg zero (196)
constexpr int CVT_SB  = (NG * D1 + 255) / 256;        // sums zero (64)

__device__ __forceinline__ void wt_one(const float* Wq, const float* Wk,
    const float* Wv, const float* Ws, short* Wt, int kbits, int i) {
  int K = 1 << kbits;
  int seg = i >> (kbits + 8);               // 0=Q 1=K 2=V 3=S
  int idx = i & ((D1 << kbits) - 1);
  int n = idx >> kbits, k = idx & (K - 1);
  const float* W = (seg == 0) ? Wq : (seg == 1) ? Wk : (seg == 2) ? Wv : Ws;
  int row;
  if (seg == 0)      row = n;
  else if (seg == 3) row = 768 + n;
  else               row = 256 + (n >> 2) * 8 + ((seg == 2) ? 4 : 0) + (n & 3);
  Wt[(size_t)row * K + k] = f2b(W[(size_t)k * D1 + n]);
}

__global__ void cvt_all_k(const float* __restrict__ x, short* __restrict__ Xb,
    const float* __restrict__ Wq1, const float* __restrict__ Wk1,
    const float* __restrict__ Wv1, const float* __restrict__ Ws1,
    const float* __restrict__ Wq2, const float* __restrict__ Wk2,
    const float* __restrict__ Wv2, const float* __restrict__ Ws2,
    short* __restrict__ Wtc1, short* __restrict__ Wtc2,
    const float* __restrict__ bq1, const float* __restrict__ bk1,
    const float* __restrict__ bv1, const float* __restrict__ bs1,
    const float* __restrict__ bq2, const float* __restrict__ bk2,
    const float* __restrict__ bv2, const float* __restrict__ bs2,
    float* __restrict__ bc1, float* __restrict__ bc2,
    int* __restrict__ deg, float* __restrict__ sums) {
  const int b = blockIdx.x;
  const int t = threadIdx.x;
  if (b < CVT_XB) {                               // x -> bf16 (4/thread)
    int i = (b * 256 + t) * 4;
    if (i >= NN * INC) return;
    float4 v = *(const float4*)(x + i);
    short4 o; o.x = f2b(v.x); o.y = f2b(v.y); o.z = f2b(v.z); o.w = f2b(v.w);
    *(short4*)(Xb + i) = o;
  } else if (b < CVT_XB + CVT_W1B) {              // layer-1 weights
    int i = (b - CVT_XB) * 256 + t;
    if (i < 4 * D1 * INC) wt_one(Wq1, Wk1, Wv1, Ws1, Wtc1, 7, i);
  } else if (b < CVT_XB + CVT_W1B + CVT_W2B) {    // layer-2 weights
    int i = (b - CVT_XB - CVT_W1B) * 256 + t;
    if (i < 4 * D1 * D1) wt_one(Wq2, Wk2, Wv2, Ws2, Wtc2, 8, i);
  } else if (b < CVT_XB + CVT_W1B + CVT_W2B + CVT_BB) {  // bias concat
    int i = (b - CVT_XB - CVT_W1B - CVT_W2B) * 256 + t;
    if (i >= 2 * D4) return;
    int row = i & (D4 - 1);
    const float* bq = (i < D4) ? bq1 : bq2;
    const float* bk = (i < D4) ? bk1 : bk2;
    const float* bv = (i < D4) ? bv1 : bv2;
    const float* bs = (i < D4) ? bs1 : bs2;
    float v;
    if (row < 256) v = bq[row];
    else if (row < 768) {
      int j = row - 256, grp = j >> 3, off = j & 7;
      int ch = grp * 4 + (off & 3);
      v = (off < 4) ? bk[ch] : bv[ch];
    } else v = bs[row - 768];
    ((i < D4) ? bc1 : bc2)[row] = v;
  } else if (b < CVT_XB + CVT_W1B + CVT_W2B + CVT_BB + CVT_DB) {  // deg = 0
    int i = (b - CVT_XB - CVT_W1B - CVT_W2B - CVT_BB) * 256 + t;
    if (i < NN) deg[i] = 0;
  } else {                                        // sums = 0
    int i = (b - CVT_XB - CVT_W1B - CVT_W2B - CVT_BB - CVT_DB) * 256 + t;
    if (i < NG * D1) sums[i] = 0.f;
  }
}

// ---------- CSR build ----------
__global__ void deg_count(const int* __restrict__ dst, int* __restrict__ deg) {
  int e = blockIdx.x * 256 + threadIdx.x;
  if (e < NE) atomicAdd(&deg[dst[e]], 1);
}
// block partial sums; extra block NB_SCAN does graph bounds (binary search)
__global__ __launch_bounds__(256) void scan1(const int* __restrict__ deg,
    int* __restrict__ partial, const int* __restrict__ batch, int* __restrict__ gb) {
  if (blockIdx.x == NB_SCAN) {
    int g = threadIdx.x;
    if (g > NG) return;
    int lo = 0, hi = NN;
    while (lo < hi) {
      int mid = (lo + hi) >> 1;
      if (batch[mid] < g) lo = mid + 1; else hi = mid;
    }
    gb[g] = lo;
    return;
  }
  __shared__ int sh[256];
  int t = threadIdx.x, i = blockIdx.x * 256 + t;
  sh[t] = (i < NN) ? deg[i] : 0;
  __syncthreads();
  for (int off = 128; off > 0; off >>= 1) {
    if (t < off) sh[t] += sh[t + off];
    __syncthreads();
  }
  if (t == 0) partial[blockIdx.x] = sh[0];
}
__global__ __launch_bounds__(256) void scan3(const int* __restrict__ deg,
    const int* __restrict__ partial, int* __restrict__ rowstart,
    int* __restrict__ cursor) {
  __shared__ int sh[256];
  __shared__ int base_s;
  const int t = threadIdx.x;
  int pv = (t < NB_SCAN) ? partial[t] : 0;
  sh[t] = pv;
  __syncthreads();
  for (int off = 1; off < 256; off <<= 1) {
    int o = (t >= off) ? sh[t - off] : 0;
    __syncthreads();
    sh[t] += o;
    __syncthreads();
  }
  if (t == 0) base_s = (blockIdx.x == 0) ? 0 : sh[blockIdx.x - 1];
  __syncthreads();
  const int base = base_s;
  __syncthreads();
  int i = blockIdx.x * 256 + t;
  int v = (i < NN) ? deg[i] : 0;
  sh[t] = v;
  __syncthreads();
  for (int off = 1; off < 256; off <<= 1) {
    int o = (t >= off) ? sh[t - off] : 0;
    __syncthreads();
    sh[t] += o;
    __syncthreads();
  }
  int excl = sh[t] - v + base;
  if (i <= NN) rowstart[i] = excl;
  if (i < NN)  cursor[i]   = excl;
}
__global__ void scatter_k(const int* __restrict__ src, const int* __restrict__ dst,
    int* __restrict__ cursor, int* __restrict__ esrc) {
  int e = blockIdx.x * 256 + threadIdx.x;
  if (e >= NE) return;
  int d = dst[e];
  int pos = atomicAdd(&cursor[d], 1);
  esrc[pos] = src[e];
}

// ---------- MFMA GEMM: [QS bf16 | KV8 fp8] = Xb[M,K] @ Wt[1024,K]^T + bias ----
// Swapped-operand MFMA (C^T fragments): lane holds 4 CONSECUTIVE output cols
// (col = quad*4+r, row = l16) -> in-register bias/bf16/fp8 epilogue, no C LDS.
// LDS staging XOR-swizzle: slot ^= (row>>1)&3 (inverse-swizzled global source,
// swizzled ds_read) kills the 8-way bank conflict of the 64B-row layout.
__global__ __launch_bounds__(256) void gemm_mfma(
    const short* __restrict__ Xb, const short* __restrict__ Wt,
    const float* __restrict__ bias, short* __restrict__ QS,
    unsigned char* __restrict__ KV8, int M, int K) {
  __shared__ short smem[4 * 4096];     // As0 | As1 | Bs0 | Bs1 (8KB each)
  short* As0 = smem;
  short* As1 = smem + 4096;
  short* Bs0 = smem + 8192;
  short* Bs1 = smem + 12288;
  const int bx = blockIdx.x;                 // 0..63
  const int by = blockIdx.y;
  const int m_tile = (bx & 7) + (by << 3);   // XCD swizzle
  const int n_tile = bx >> 3;                // 0..7
  const int m0 = m_tile * 128;
  if (m0 >= M) return;
  const int n0 = n_tile * 128;

  const int t    = threadIdx.x;
  const int lane = t & 63;
  const int wv   = t >> 6;
  const int wm   = (wv >> 1) * 64;
  const int wn   = (wv & 1) * 64;
  const int quad = lane >> 4;
  const int l16  = lane & 15;
  const int lrow = lane >> 2;
  const int lseg = lane & 3;

  const int swz_w = (lseg ^ ((lrow >> 1) & 3)) * 8;   // staging source swizzle
  const int swz_r = (quad ^ ((l16 >> 1) & 3)) * 8;    // fragment read swizzle

  f32x4 acc[4][4] = {};
  for (int k0 = 0; k0 < K; k0 += 64) {
#pragma unroll
    for (int j = 0; j < 2; ++j) {
      const int rb = wv * 32 + j * 16;
      int gm = m0 + rb + lrow;
      gm = gm < M ? gm : M - 1;                        // clamp (stores guarded)
      const size_t ga = (size_t)gm * K + k0 + swz_w;
      gld_lds16(Xb + ga,      &As0[rb * 32]);
      gld_lds16(Xb + ga + 32, &As1[rb * 32]);
      const size_t gw = (size_t)(n0 + rb + lrow) * K + k0 + swz_w;
      gld_lds16(Wt + gw,      &Bs0[rb * 32]);
      gld_lds16(Wt + gw + 32, &Bs1[rb * 32]);
    }
    __syncthreads();
    {
      bf16x8 a[4], b[4];
#pragma unroll
      for (int mi = 0; mi < 4; mi++)
        a[mi] = *(const bf16x8*)(&As0[(wm + mi * 16 + l16) * 32 + swz_r]);
#pragma unroll
      for (int nj = 0; nj < 4; nj++)
        b[nj] = *(const bf16x8*)(&Bs0[(wn + nj * 16 + l16) * 32 + swz_r]);
#pragma unroll
      for (int mi = 0; mi < 4; mi++)
#pragma unroll
        for (int nj = 0; nj < 4; nj++)
          acc[mi][nj] = __builtin_amdgcn_mfma_f32_16x16x32_bf16(b[nj], a[mi], acc[mi][nj], 0, 0, 0);
#pragma unroll
      for (int mi = 0; mi < 4; mi++)
        a[mi] = *(const bf16x8*)(&As1[(wm + mi * 16 + l16) * 32 + swz_r]);
#pragma unroll
      for (int nj = 0; nj < 4; nj++)
        b[nj] = *(const bf16x8*)(&Bs1[(wn + nj * 16 + l16) * 32 + swz_r]);
#pragma unroll
      for (int mi = 0; mi < 4; mi++)
#pragma unroll
        for (int nj = 0; nj < 4; nj++)
          acc[mi][nj] = __builtin_amdgcn_mfma_f32_16x16x32_bf16(b[nj], a[mi], acc[mi][nj], 0, 0, 0);
    }
    __syncthreads();
  }
  // ---- epilogue: fully in-register (C^T fragment: 4 consecutive cols/lane) --
  const bool isKV = (n_tile >= 2) && (n_tile <= 5);
  float4 bz[4];
#pragma unroll
  for (int nj = 0; nj < 4; nj++)
    bz[nj] = *(const float4*)(bias + n0 + wn + nj * 16 + quad * 4);
#pragma unroll
  for (int mi = 0; mi < 4; mi++) {
    const int m = m0 + wm + mi * 16 + l16;
    if (m >= M) continue;
#pragma unroll
    for (int nj = 0; nj < 4; nj++) {
      const int col = n0 + wn + nj * 16 + quad * 4;
      const float v0 = acc[mi][nj][0] + bz[nj].x;
      const float v1 = acc[mi][nj][1] + bz[nj].y;
      const float v2 = acc[mi][nj][2] + bz[nj].z;
      const float v3 = acc[mi][nj][3] + bz[nj].w;
      if (isKV) {
        const int p = pk_fp8x4(v0, v1, v2, v3);
        *(int*)(KV8 + (size_t)m * 512 + (col - 256)) = p;
      } else {
        short4 o;
        o.x = f2b(v0); o.y = f2b(v1); o.z = f2b(v2); o.w = f2b(v3);
        const int qc = (n_tile < 2) ? col : (col - 512);
        *(short4*)(QS + (size_t)m * 512 + qc) = o;
      }
    }
  }
}

// ---------- fp8 KV decode ----------
__device__ __forceinline__ void dec_kv(const int2 x, float* k, float* v) {
  f32x2 a = __builtin_amdgcn_cvt_pk_f32_fp8(x.x, false);
  f32x2 b = __builtin_amdgcn_cvt_pk_f32_fp8(x.x, true);
  f32x2 c = __builtin_amdgcn_cvt_pk_f32_fp8(x.y, false);
  f32x2 d = __builtin_amdgcn_cvt_pk_f32_fp8(x.y, true);
  k[0] = a.x; k[1] = a.y; k[2] = b.x; k[3] = b.y;
  v[0] = c.x; v[1] = c.y; v[2] = d.x; v[3] = d.y;
}

// ---------- fused attention: online softmax, fp8 KV, 8-edge MLP ----------
template <typename TOUT>
__device__ __forceinline__ void st1(TOUT* p, float v);
template <> __device__ __forceinline__ void st1<float>(float* p, float v) { *p = v; }
template <> __device__ __forceinline__ void st1<short>(short* p, float v) { *p = f2b(v); }

template <typename TOUT>
__global__ __launch_bounds__(256) void node_attn(
    const int* __restrict__ rowstart, const int* __restrict__ esrc,
    const short* __restrict__ QS, const unsigned char* __restrict__ KV8,
    TOUT* __restrict__ out) {
  const int nid = blockIdx.x * 4 + (threadIdx.x >> 6);
  if (nid >= NN) return;
  const int t  = threadIdx.x & 63;
  const int c0 = t * 4;
  const int r0 = __builtin_amdgcn_readfirstlane(rowstart[nid]);
  const int r1 = __builtin_amdgcn_readfirstlane(rowstart[nid + 1]);
  const float4 q = ld4b(QS + (size_t)nid * 512 + c0);
  const unsigned char* kvb = KV8 + t * 8;
  float m = -INFINITY, denom = 0.f;
  float4 acc = make_float4(0.f, 0.f, 0.f, 0.f);
  int r = r0;
  for (; r + 7 < r1; r += 8) {
    // scalar edge indices -> SGPR base for the gathers; 8 loads in flight
    const int e0 = __builtin_amdgcn_readfirstlane(esrc[r + 0]);
    const int e1 = __builtin_amdgcn_readfirstlane(esrc[r + 1]);
    const int e2 = __builtin_amdgcn_readfirstlane(esrc[r + 2]);
    const int e3 = __builtin_amdgcn_readfirstlane(esrc[r + 3]);
    const int e4 = __builtin_amdgcn_readfirstlane(esrc[r + 4]);
    const int e5 = __builtin_amdgcn_readfirstlane(esrc[r + 5]);
    const int e6 = __builtin_amdgcn_readfirstlane(esrc[r + 6]);
    const int e7 = __builtin_amdgcn_readfirstlane(esrc[r + 7]);
    const int2 x0 = *(const int2*)(kvb + (size_t)e0 * 512);
    const int2 x1 = *(const int2*)(kvb + (size_t)e1 * 512);
    const int2 x2 = *(const int2*)(kvb + (size_t)e2 * 512);
    const int2 x3 = *(const int2*)(kvb + (size_t)e3 * 512);
    const int2 x4 = *(const int2*)(kvb + (size_t)e4 * 512);
    const int2 x5 = *(const int2*)(kvb + (size_t)e5 * 512);
    const int2 x6 = *(const int2*)(kvb + (size_t)e6 * 512);
    const int2 x7 = *(const int2*)(kvb + (size_t)e7 * 512);
    float k0[4], v0[4], k1[4], v1[4], k2[4], v2[4], k3[4], v3[4];
    float k4[4], v4[4], k5[4], v5[4], k6[4], v6[4], k7[4], v7[4];
    dec_kv(x0, k0, v0); dec_kv(x1, k1, v1);
    dec_kv(x2, k2, v2); dec_kv(x3, k3, v3);
    dec_kv(x4, k4, v4); dec_kv(x5, k5, v5);
    dec_kv(x6, k6, v6); dec_kv(x7, k7, v7);
    float d0 = q.x * k0[0] + q.y * k0[1] + q.z * k0[2] + q.w * k0[3];
    float d1 = q.x * k1[0] + q.y * k1[1] + q.z * k1[2] + q.w * k1[3];
    float d2 = q.x * k2[0] + q.y * k2[1] + q.z * k2[2] + q.w * k2[3];
    float d3 = q.x * k3[0] + q.y * k3[1] + q.z * k3[2] + q.w * k3[3];
    float d4 = q.x * k4[0] + q.y * k4[1] + q.z * k4[2] + q.w * k4[3];
    float d5 = q.x * k5[0] + q.y * k5[1] + q.z * k5[2] + q.w * k5[3];
    float d6 = q.x * k6[0] + q.y * k6[1] + q.z * k6[2] + q.w * k6[3];
    float d7 = q.x * k7[0] + q.y * k7[1] + q.z * k7[2] + q.w * k7[3];
#pragma unroll
    for (int off = 1; off <= 8; off <<= 1) {
      d0 += __shfl_xor(d0, off, 16);
      d1 += __shfl_xor(d1, off, 16);
      d2 += __shfl_xor(d2, off, 16);
      d3 += __shfl_xor(d3, off, 16);
      d4 += __shfl_xor(d4, off, 16);
      d5 += __shfl_xor(d5, off, 16);
      d6 += __shfl_xor(d6, off, 16);
      d7 += __shfl_xor(d7, off, 16);
    }
    d0 *= 0.125f; d1 *= 0.125f; d2 *= 0.125f; d3 *= 0.125f;
    d4 *= 0.125f; d5 *= 0.125f; d6 *= 0.125f; d7 *= 0.125f;
    const float t01 = fmaxf(d0, d1), t23 = fmaxf(d2, d3);
    const float t45 = fmaxf(d4, d5), t67 = fmaxf(d6, d7);
    const float nm = fmaxf(fmaxf(m, fmaxf(t01, t23)), fmaxf(t45, t67));
    const float sc  = __expf(m - nm);
    const float ex0 = __expf(d0 - nm);
    const float ex1 = __expf(d1 - nm);
    const float ex2 = __expf(d2 - nm);
    const float ex3 = __expf(d3 - nm);
    const float ex4 = __expf(d4 - nm);
    const float ex5 = __expf(d5 - nm);
    const float ex6 = __expf(d6 - nm);
    const float ex7 = __expf(d7 - nm);
    denom = denom * sc + ((ex0 + ex1) + (ex2 + ex3)) + ((ex4 + ex5) + (ex6 + ex7));
    acc.x = acc.x * sc + ex0 * v0[0] + ex1 * v1[0] + ex2 * v2[0] + ex3 * v3[0]
                       + ex4 * v4[0] + ex5 * v5[0] + ex6 * v6[0] + ex7 * v7[0];
    acc.y = acc.y * sc + ex0 * v0[1] + ex1 * v1[1] + ex2 * v2[1] + ex3 * v3[1]
                       + ex4 * v4[1] + ex5 * v5[1] + ex6 * v6[1] + ex7 * v7[1];
    acc.z = acc.z * sc + ex0 * v0[2] + ex1 * v1[2] + ex2 * v2[2] + ex3 * v3[2]
                       + ex4 * v4[2] + ex5 * v5[2] + ex6 * v6[2] + ex7 * v7[2];
    acc.w = acc.w * sc + ex0 * v0[3] + ex1 * v1[3] + ex2 * v2[3] + ex3 * v3[3]
                       + ex4 * v4[3] + ex5 * v5[3] + ex6 * v6[3] + ex7 * v7[3];
    m = nm;
  }
  for (; r + 3 < r1; r += 4) {
    const int e0 = __builtin_amdgcn_readfirstlane(esrc[r + 0]);
    const int e1 = __builtin_amdgcn_readfirstlane(esrc[r + 1]);
    const int e2 = __builtin_amdgcn_readfirstlane(esrc[r + 2]);
    const int e3 = __builtin_amdgcn_readfirstlane(esrc[r + 3]);
    const int2 x0 = *(const int2*)(kvb + (size_t)e0 * 512);
    const int2 x1 = *(const int2*)(kvb + (size_t)e1 * 512);
    const int2 x2 = *(const int2*)(kvb + (size_t)e2 * 512);
    const int2 x3 = *(const int2*)(kvb + (size_t)e3 * 512);
    float k0[4], v0[4], k1[4], v1[4], k2[4], v2[4], k3[4], v3[4];
    dec_kv(x0, k0, v0); dec_kv(x1, k1, v1);
    dec_kv(x2, k2, v2); dec_kv(x3, k3, v3);
    float d0 = q.x * k0[0] + q.y * k0[1] + q.z * k0[2] + q.w * k0[3];
    float d1 = q.x * k1[0] + q.y * k1[1] + q.z * k1[2] + q.w * k1[3];
    float d2 = q.x * k2[0] + q.y * k2[1] + q.z * k2[2] + q.w * k2[3];
    float d3 = q.x * k3[0] + q.y * k3[1] + q.z * k3[2] + q.w * k3[3];
#pragma unroll
    for (int off = 1; off <= 8; off <<= 1) {
      d0 += __shfl_xor(d0, off, 16);
      d1 += __shfl_xor(d1, off, 16);
      d2 += __shfl_xor(d2, off, 16);
      d3 += __shfl_xor(d3, off, 16);
    }
    d0 *= 0.125f; d1 *= 0.125f; d2 *= 0.125f; d3 *= 0.125f;
    const float nm = fmaxf(fmaxf(m, fmaxf(d0, d1)), fmaxf(d2, d3));
    const float sc = __expf(m - nm);
    const float ex0 = __expf(d0 - nm);
    const float ex1 = __expf(d1 - nm);
    const float ex2 = __expf(d2 - nm);
    const float ex3 = __expf(d3 - nm);
    denom = denom * sc + ex0 + ex1 + ex2 + ex3;
    acc.x = acc.x * sc + ex0 * v0[0] + ex1 * v1[0] + ex2 * v2[0] + ex3 * v3[0];
    acc.y = acc.y * sc + ex0 * v0[1] + ex1 * v1[1] + ex2 * v2[1] + ex3 * v3[1];
    acc.z = acc.z * sc + ex0 * v0[2] + ex1 * v1[2] + ex2 * v2[2] + ex3 * v3[2];
    acc.w = acc.w * sc + ex0 * v0[3] + ex1 * v1[3] + ex2 * v2[3] + ex3 * v3[3];
    m = nm;
  }
  for (; r < r1; r++) {
    const int e0 = __builtin_amdgcn_readfirstlane(esrc[r]);
    const int2 x0 = *(const int2*)(kvb + (size_t)e0 * 512);
    float k0[4], v0[4];
    dec_kv(x0, k0, v0);
    float d0 = q.x * k0[0] + q.y * k0[1] + q.z * k0[2] + q.w * k0[3];
#pragma unroll
    for (int off = 1; off <= 8; off <<= 1) d0 += __shfl_xor(d0, off, 16);
    d0 *= 0.125f;
    const float nm = fmaxf(m, d0);
    const float sc = __expf(m - nm);
    const float ex0 = __expf(d0 - nm);
    denom = denom * sc + ex0;
    acc.x = acc.x * sc + ex0 * v0[0];
    acc.y = acc.y * sc + ex0 * v0[1];
    acc.z = acc.z * sc + ex0 * v0[2];
    acc.w = acc.w * sc + ex0 * v0[3];
    m = nm;
  }
  const float inv = 1.0f / (denom + 1e-16f);
  const float4 sk = ld4b(QS + (size_t)nid * 512 + 256 + c0);
  float o0 = acc.x * inv + sk.x;
  float o1 = acc.y * inv + sk.y;
  float o2 = acc.z * inv + sk.z;
  float o3 = acc.w * inv + sk.w;
  o0 = o0 > 0.f ? o0 : expm1f(o0);
  o1 = o1 > 0.f ? o1 : expm1f(o1);
  o2 = o2 > 0.f ? o2 : expm1f(o2);
  o3 = o3 > 0.f ? o3 : expm1f(o3);
  TOUT* p = out + (size_t)nid * D1 + c0;
  st1<TOUT>(p + 0, o0); st1<TOUT>(p + 1, o1);
  st1<TOUT>(p + 2, o2); st1<TOUT>(p + 3, o3);
}

// ---------- mean-pool partial sums (parallel, run-length atomics) ----------
__global__ __launch_bounds__(256) void pool_k(const float* __restrict__ h,
    const int* __restrict__ batch, float* __restrict__ sums) {
  const int c = threadIdx.x;
  const int n0 = blockIdx.x * 64;
  const int n1 = min(n0 + 64, NN);
  float run = 0.f;
  int curg = -1;
  for (int n = n0; n < n1; n++) {
    int g = batch[n];
    if (g != curg) {
      if (curg >= 0) atomicAdd(&sums[(size_t)curg * D1 + c], run);
      run = 0.f; curg = g;
    }
    run += h[(size_t)n * D1 + c];
  }
  if (curg >= 0) atomicAdd(&sums[(size_t)curg * D1 + c], run);
}

// ---------- classifier + log_softmax (counts from gb) ----------
__global__ __launch_bounds__(640) void head_k(const float* __restrict__ sums,
    const int* __restrict__ gb, const float* __restrict__ Wl,
    const float* __restrict__ bl, float* __restrict__ out) {
  __shared__ float logits[NG][NOUT];
  const int t = threadIdx.x;
  if (t < NG * NOUT) {
    int g = t / NOUT, o = t % NOUT;
    float inv = 1.0f / fmaxf((float)(gb[g + 1] - gb[g]), 1.0f);
    float acc = 0.f;
    for (int k = 0; k < D1; k++) acc += sums[(size_t)g * D1 + k] * Wl[k * NOUT + o];
    logits[g][o] = acc * inv + bl[o];
  }
  __syncthreads();
  if (t < NG) {
    float mx = -INFINITY;
#pragma unroll
    for (int o = 0; o < NOUT; o++) mx = fmaxf(mx, logits[t][o]);
    float s = 0.f;
#pragma unroll
    for (int o = 0; o < NOUT; o++) s += __expf(logits[t][o] - mx);
    float lse = mx + logf(s);
#pragma unroll
    for (int o = 0; o < NOUT; o++) out[t * NOUT + o] = logits[t][o] - lse;
  }
}

// ---------------------------------------------------------------------------
extern "C" void kernel_launch(void* const* d_in, const int* in_sizes, int n_in,
                              void* d_out, int out_size, void* d_ws, size_t ws_size,
                              hipStream_t stream) {
  const float* x   = (const float*)d_in[0];
  const int* ei    = (const int*)d_in[1];
  const int* batch = (const int*)d_in[2];
  const float* Wq1 = (const float*)d_in[3];  const float* bq1 = (const float*)d_in[4];
  const float* Wk1 = (const float*)d_in[5];  const float* bk1 = (const float*)d_in[6];
  const float* Wv1 = (const float*)d_in[7];  const float* bv1 = (const float*)d_in[8];
  const float* Ws1 = (const float*)d_in[9];  const float* bs1 = (const float*)d_in[10];
  const float* Wq2 = (const float*)d_in[11]; const float* bq2 = (const float*)d_in[12];
  const float* Wk2 = (const float*)d_in[13]; const float* bk2 = (const float*)d_in[14];
  const float* Wv2 = (const float*)d_in[15]; const float* bv2 = (const float*)d_in[16];
  const float* Ws2 = (const float*)d_in[17]; const float* bs2 = (const float*)d_in[18];
  const float* Wl  = (const float*)d_in[19]; const float* bl  = (const float*)d_in[20];

  const int* srcIdx = ei;          // edge_index[0] (source j)
  const int* dstIdx = ei + NE;     // edge_index[1] (target i)

  // -------- workspace layout --------
  float* ws = (float*)d_ws;
  const size_t SZ_NODE = (size_t)NN * D1;       // 12.8M elems
  float* H2f  = ws;                              // NN*D1 fp32
  float* sums = ws + SZ_NODE;                    // NG*D1
  float* bc1  = sums + (size_t)NG * D1;          // 1024
  float* bc2  = bc1 + D4;                        // 1024
  short* Xb   = (short*)(bc2 + D4);              // NN*INC
  short* H1b  = Xb + (size_t)NN * INC;           // NN*D1
  short* QS   = H1b + SZ_NODE;                   // NN*512 bf16 (Q|S)
  short* Wtc1 = QS + (size_t)NN * 512;           // 1024*128
  short* Wtc2 = Wtc1 + (size_t)D4 * INC;         // 1024*256
  unsigned char* KV8 = (unsigned char*)(Wtc2 + (size_t)D4 * D1);  // NN*512 fp8
  int* ip      = (int*)(KV8 + (size_t)NN * 512);
  int* deg     = ip;                 // NN
  int* partial = deg + NN;           // 256
  int* rowstart= partial + 256;      // NN+1
  int* cursor  = rowstart + NN + 1;  // NN
  int* esrc    = cursor + NN;        // NE
  int* gb      = esrc + NE;          // NG+1

  const int mtiles = (NN + 127) / 128;           // 391
  const dim3 gemmGrid(64, (mtiles + 7) / 8);     // 64 x 49 swizzled
  const int edgeBlocks = (NE + 255) / 256;
  const int aggBlocks  = (NN + 3) / 4;
  const int cvtBlocks  = CVT_XB + CVT_W1B + CVT_W2B + CVT_BB + CVT_DB + CVT_SB;

  // ======== Converts + zeroing (one kernel) ========
  cvt_all_k<<<cvtBlocks, 256, 0, stream>>>(x, Xb,
      Wq1, Wk1, Wv1, Ws1, Wq2, Wk2, Wv2, Ws2, Wtc1, Wtc2,
      bq1, bk1, bv1, bs1, bq2, bk2, bv2, bs2, bc1, bc2, deg, sums);

  // ======== CSR build + graph bounds ========
  deg_count<<<edgeBlocks, 256, 0, stream>>>(dstIdx, deg);
  scan1<<<NB_SCAN + 1, 256, 0, stream>>>(deg, partial, batch, gb);
  scan3<<<NB_SCAN, 256, 0, stream>>>(deg, partial, rowstart, cursor);
  scatter_k<<<edgeBlocks, 256, 0, stream>>>(srcIdx, dstIdx, cursor, esrc);

  // ======== Layer 1 ========
  gemm_mfma<<<gemmGrid, 256, 0, stream>>>(Xb, Wtc1, bc1, QS, KV8, NN, INC);
  node_attn<short><<<aggBlocks, 256, 0, stream>>>(rowstart, esrc, QS, KV8, H1b);

  // ======== Layer 2 ========
  gemm_mfma<<<gemmGrid, 256, 0, stream>>>(H1b, Wtc2, bc2, QS, KV8, NN, D1);
  node_attn<float><<<aggBlocks, 256, 0, stream>>>(rowstart, esrc, QS, KV8, H2f);

  // ======== Pool + head ========
  pool_k<<<(NN + 63) / 64, 256, 0, stream>>>(H2f, batch, sums);
  head_k<<<1, 640, 0, stream>>>(sums, gb, Wl, bl, (float*)d_out);
}

// Round 3
// 363.758 us; speedup vs baseline: 1.0944x; 1.0944x over previous
//
#include <hip/hip_runtime.h>
#include <math.h>

constexpr int NN   = 50000;   // nodes
constexpr int NE   = 400000;  // edges
constexpr int INC  = 128;     // in channels
constexpr int NH   = 4;       // heads
constexpr int D1   = 256;     // NH*HIDC
constexpr int D4   = 1024;    // 4*D1 fused QKVS logical cols
constexpr int NOUT = 10;      // classes
constexpr int NG   = 64;      // graphs
constexpr int NB_SCAN = (NN + 255) / 256;   // 196 scan blocks

// GEMM output split per node:
//   QS[node][512] bf16 : cols 0..255 = Q, cols 256..511 = S
//   KV8[node][512] fp8 : byte j -> group g=j>>3, off=j&7: off<4 -> K ch 4g+off,
//                                                        off>=4 -> V ch 4g+(off-4)
// Lane t of node_attn reads 8 B at node*512 + t*8 = [K c0..c0+3 | V c0..c0+3].

typedef __attribute__((ext_vector_type(8))) short bf16x8;   // MFMA A/B frag
typedef __attribute__((ext_vector_type(4))) float f32x4;    // MFMA C/D frag
typedef __attribute__((ext_vector_type(2))) float f32x2;

// ---------- bf16 helpers ----------
__device__ __forceinline__ short f2b(float f) {
  union { float f; unsigned int i; } v; v.f = f;
  unsigned int x = v.i;
  return (short)((x + 0x7FFFu + ((x >> 16) & 1u)) >> 16);
}
__device__ __forceinline__ float b2f(short u) {
  union { unsigned int i; float f; } v; v.i = ((unsigned int)(unsigned short)u) << 16;
  return v.f;
}
__device__ __forceinline__ float4 ld4b(const short* p) {
  short4 u = *(const short4*)p;
  return make_float4(b2f(u.x), b2f(u.y), b2f(u.z), b2f(u.w));
}
// pack 4 floats -> 4 fp8 e4m3 bytes (HW convert)
__device__ __forceinline__ int pk_fp8x4(float a, float b, float c, float d) {
  int v = __builtin_amdgcn_cvt_pk_fp8_f32(a, b, 0, false);
  v = __builtin_amdgcn_cvt_pk_fp8_f32(c, d, v, true);
  return v;
}

// ---------- async global->LDS 16B ----------
__device__ __forceinline__ void gld_lds16(const short* g, short* l) {
  __builtin_amdgcn_global_load_lds(
      (const __attribute__((address_space(1))) unsigned int*)g,
      (__attribute__((address_space(3))) unsigned int*)l, 16, 0, 0);
}

// ---------- fused converts + zeroing (one dispatch) ----------
constexpr int CVT_XB  = (NN * INC / 4 + 255) / 256;   // 6250 blocks
constexpr int CVT_W1B = (4 * D1 * INC + 255) / 256;   // 512
constexpr int CVT_W2B = (4 * D1 * D1 + 255) / 256;    // 1024
constexpr int CVT_BB  = 8;                            // bias blocks
constexpr int CVT_DB  = (NN + 255) / 256;             // deg zero (196)
constexpr int CVT_SB  = (NG * D1 + 255) / 256;        // sums zero (64)

__device__ __forceinline__ void wt_one(const float* Wq, const float* Wk,
    const float* Wv, const float* Ws, short* Wt, int kbits, int i) {
  int K = 1 << kbits;
  int seg = i >> (kbits + 8);               // 0=Q 1=K 2=V 3=S
  int idx = i & ((D1 << kbits) - 1);
  int n = idx >> kbits, k = idx & (K - 1);
  const float* W = (seg == 0) ? Wq : (seg == 1) ? Wk : (seg == 2) ? Wv : Ws;
  int row;
  if (seg == 0)      row = n;
  else if (seg == 3) row = 768 + n;
  else               row = 256 + (n >> 2) * 8 + ((seg == 2) ? 4 : 0) + (n & 3);
  Wt[(size_t)row * K + k] = f2b(W[(size_t)k * D1 + n]);
}

__global__ void cvt_all_k(const float* __restrict__ x, short* __restrict__ Xb,
    const float* __restrict__ Wq1, const float* __restrict__ Wk1,
    const float* __restrict__ Wv1, const float* __restrict__ Ws1,
    const float* __restrict__ Wq2, const float* __restrict__ Wk2,
    const float* __restrict__ Wv2, const float* __restrict__ Ws2,
    short* __restrict__ Wtc1, short* __restrict__ Wtc2,
    const float* __restrict__ bq1, const float* __restrict__ bk1,
    const float* __restrict__ bv1, const float* __restrict__ bs1,
    const float* __restrict__ bq2, const float* __restrict__ bk2,
    const float* __restrict__ bv2, const float* __restrict__ bs2,
    float* __restrict__ bc1, float* __restrict__ bc2,
    int* __restrict__ deg, float* __restrict__ sums) {
  const int b = blockIdx.x;
  const int t = threadIdx.x;
  if (b < CVT_XB) {                               // x -> bf16 (4/thread)
    int i = (b * 256 + t) * 4;
    if (i >= NN * INC) return;
    float4 v = *(const float4*)(x + i);
    short4 o; o.x = f2b(v.x); o.y = f2b(v.y); o.z = f2b(v.z); o.w = f2b(v.w);
    *(short4*)(Xb + i) = o;
  } else if (b < CVT_XB + CVT_W1B) {              // layer-1 weights
    int i = (b - CVT_XB) * 256 + t;
    if (i < 4 * D1 * INC) wt_one(Wq1, Wk1, Wv1, Ws1, Wtc1, 7, i);
  } else if (b < CVT_XB + CVT_W1B + CVT_W2B) {    // layer-2 weights
    int i = (b - CVT_XB - CVT_W1B) * 256 + t;
    if (i < 4 * D1 * D1) wt_one(Wq2, Wk2, Wv2, Ws2, Wtc2, 8, i);
  } else if (b < CVT_XB + CVT_W1B + CVT_W2B + CVT_BB) {  // bias concat
    int i = (b - CVT_XB - CVT_W1B - CVT_W2B) * 256 + t;
    if (i >= 2 * D4) return;
    int row = i & (D4 - 1);
    const float* bq = (i < D4) ? bq1 : bq2;
    const float* bk = (i < D4) ? bk1 : bk2;
    const float* bv = (i < D4) ? bv1 : bv2;
    const float* bs = (i < D4) ? bs1 : bs2;
    float v;
    if (row < 256) v = bq[row];
    else if (row < 768) {
      int j = row - 256, grp = j >> 3, off = j & 7;
      int ch = grp * 4 + (off & 3);
      v = (off < 4) ? bk[ch] : bv[ch];
    } else v = bs[row - 768];
    ((i < D4) ? bc1 : bc2)[row] = v;
  } else if (b < CVT_XB + CVT_W1B + CVT_W2B + CVT_BB + CVT_DB) {  // deg = 0
    int i = (b - CVT_XB - CVT_W1B - CVT_W2B - CVT_BB) * 256 + t;
    if (i < NN) deg[i] = 0;
  } else {                                        // sums = 0
    int i = (b - CVT_XB - CVT_W1B - CVT_W2B - CVT_BB - CVT_DB) * 256 + t;
    if (i < NG * D1) sums[i] = 0.f;
  }
}

// ---------- CSR build ----------
__global__ void deg_count(const int* __restrict__ dst, int* __restrict__ deg) {
  int e = blockIdx.x * 256 + threadIdx.x;
  if (e < NE) atomicAdd(&deg[dst[e]], 1);
}
// block partial sums; extra block NB_SCAN does graph bounds (binary search)
__global__ __launch_bounds__(256) void scan1(const int* __restrict__ deg,
    int* __restrict__ partial, const int* __restrict__ batch, int* __restrict__ gb) {
  if (blockIdx.x == NB_SCAN) {
    int g = threadIdx.x;
    if (g > NG) return;
    int lo = 0, hi = NN;
    while (lo < hi) {
      int mid = (lo + hi) >> 1;
      if (batch[mid] < g) lo = mid + 1; else hi = mid;
    }
    gb[g] = lo;
    return;
  }
  __shared__ int sh[256];
  int t = threadIdx.x, i = blockIdx.x * 256 + t;
  sh[t] = (i < NN) ? deg[i] : 0;
  __syncthreads();
  for (int off = 128; off > 0; off >>= 1) {
    if (t < off) sh[t] += sh[t + off];
    __syncthreads();
  }
  if (t == 0) partial[blockIdx.x] = sh[0];
}
__global__ __launch_bounds__(256) void scan3(const int* __restrict__ deg,
    const int* __restrict__ partial, int* __restrict__ rowstart,
    int* __restrict__ cursor) {
  __shared__ int sh[256];
  __shared__ int base_s;
  const int t = threadIdx.x;
  int pv = (t < NB_SCAN) ? partial[t] : 0;
  sh[t] = pv;
  __syncthreads();
  for (int off = 1; off < 256; off <<= 1) {
    int o = (t >= off) ? sh[t - off] : 0;
    __syncthreads();
    sh[t] += o;
    __syncthreads();
  }
  if (t == 0) base_s = (blockIdx.x == 0) ? 0 : sh[blockIdx.x - 1];
  __syncthreads();
  const int base = base_s;
  __syncthreads();
  int i = blockIdx.x * 256 + t;
  int v = (i < NN) ? deg[i] : 0;
  sh[t] = v;
  __syncthreads();
  for (int off = 1; off < 256; off <<= 1) {
    int o = (t >= off) ? sh[t - off] : 0;
    __syncthreads();
    sh[t] += o;
    __syncthreads();
  }
  int excl = sh[t] - v + base;
  if (i <= NN) rowstart[i] = excl;
  if (i < NN)  cursor[i]   = excl;
}
__global__ void scatter_k(const int* __restrict__ src, const int* __restrict__ dst,
    int* __restrict__ cursor, int* __restrict__ esrc) {
  int e = blockIdx.x * 256 + threadIdx.x;
  if (e >= NE) return;
  int d = dst[e];
  int pos = atomicAdd(&cursor[d], 1);
  esrc[pos] = src[e];
}

// ---------- MFMA GEMM: [QS bf16 | KV8 fp8] = Xb[M,K] @ Wt[1024,K]^T + bias ----
// Swapped-operand MFMA (C^T fragments): lane holds 4 CONSECUTIVE output cols
// (col = quad*4+r, row = l16). XOR-swizzled LDS staging (conflict-free K-loop,
// verified round 2). Double-buffered K-step=32 pipeline: prefetch tile k+1
// while computing tile k; ONE barrier per step. Epilogue: LDS-staged C tile
// (ds_write_b64 bf16 / ds_write_b32 pre-packed fp8) + coalesced copy-out.
constexpr int CLDS = 136;   // C-tile LDS stride in shorts

__global__ __launch_bounds__(256) void gemm_mfma(
    const short* __restrict__ Xb, const short* __restrict__ Wt,
    const float* __restrict__ bias, short* __restrict__ QS,
    unsigned char* __restrict__ KV8, int M, int K) {
  __shared__ short smem[128 * CLDS];   // 34816 B; staging aliases first 32 KB
  const int bx = blockIdx.x;                 // 0..63
  const int by = blockIdx.y;
  const int m_tile = (bx & 7) + (by << 3);   // XCD swizzle
  const int n_tile = bx >> 3;                // 0..7
  const int m0 = m_tile * 128;
  if (m0 >= M) return;
  const int n0 = n_tile * 128;

  const int t    = threadIdx.x;
  const int lane = t & 63;
  const int wv   = t >> 6;
  const int wm   = (wv >> 1) * 64;
  const int wn   = (wv & 1) * 64;
  const int quad = lane >> 4;
  const int l16  = lane & 15;
  const int lrow = lane >> 2;
  const int lseg = lane & 3;

  const int swz_w = (lseg ^ ((lrow >> 1) & 3)) * 8;   // staging source swizzle
  const int swz_r = (quad ^ ((l16 >> 1) & 3)) * 8;    // fragment read swizzle

  // buffers (shorts): A0 [0,4096) B0 [4096,8192) A1 [8192,12288) B1 [12288,16384)
  f32x4 acc[4][4] = {};

  // prologue: stage tile k0=0 into buffer 0
  {
#pragma unroll
    for (int j = 0; j < 2; ++j) {
      const int rb = (wv * 2 + j) * 16;      // 16 rows per issue per matrix
      int gm = m0 + rb + lrow;
      gm = gm < M ? gm : M - 1;
      gld_lds16(Xb + (size_t)gm * K + swz_w,              &smem[rb * 32]);
      gld_lds16(Wt + (size_t)(n0 + rb + lrow) * K + swz_w, &smem[4096 + rb * 32]);
    }
  }
  __syncthreads();

  int cur = 0;
  for (int k0 = 0; k0 < K; k0 += 32) {
    // prefetch next K-tile into the other buffer (overlaps with compute)
    if (k0 + 32 < K) {
      short* An = &smem[(cur ^ 1) * 8192];
      short* Bn = &smem[(cur ^ 1) * 8192 + 4096];
#pragma unroll
      for (int j = 0; j < 2; ++j) {
        const int rb = (wv * 2 + j) * 16;
        int gm = m0 + rb + lrow;
        gm = gm < M ? gm : M - 1;
        gld_lds16(Xb + (size_t)gm * K + k0 + 32 + swz_w,              &An[rb * 32]);
        gld_lds16(Wt + (size_t)(n0 + rb + lrow) * K + k0 + 32 + swz_w, &Bn[rb * 32]);
      }
    }
    // compute current buffer
    {
      const short* Ac = &smem[cur * 8192];
      const short* Bc = &smem[cur * 8192 + 4096];
      bf16x8 a[4], b[4];
#pragma unroll
      for (int mi = 0; mi < 4; mi++)
        a[mi] = *(const bf16x8*)(&Ac[(wm + mi * 16 + l16) * 32 + swz_r]);
#pragma unroll
      for (int nj = 0; nj < 4; nj++)
        b[nj] = *(const bf16x8*)(&Bc[(wn + nj * 16 + l16) * 32 + swz_r]);
#pragma unroll
      for (int mi = 0; mi < 4; mi++)
#pragma unroll
        for (int nj = 0; nj < 4; nj++)
          acc[mi][nj] = __builtin_amdgcn_mfma_f32_16x16x32_bf16(b[nj], a[mi], acc[mi][nj], 0, 0, 0);
    }
    __syncthreads();   // waits prefetch (vmcnt) + guards buffer reuse
    cur ^= 1;
  }

  // ---- epilogue: bias + pack in-register, stage in LDS, coalesced copy-out --
  const bool isKV = (n_tile >= 2) && (n_tile <= 5);
  float4 bz[4];
#pragma unroll
  for (int nj = 0; nj < 4; nj++)
    bz[nj] = *(const float4*)(bias + n0 + wn + nj * 16 + quad * 4);

  if (isKV) {
    unsigned char* cs = (unsigned char*)smem;      // [128][136] bytes
#pragma unroll
    for (int mi = 0; mi < 4; mi++) {
      const int row = wm + mi * 16 + l16;
#pragma unroll
      for (int nj = 0; nj < 4; nj++) {
        const int colb = wn + nj * 16 + quad * 4;
        const int p = pk_fp8x4(acc[mi][nj][0] + bz[nj].x, acc[mi][nj][1] + bz[nj].y,
                               acc[mi][nj][2] + bz[nj].z, acc[mi][nj][3] + bz[nj].w);
        *(int*)(cs + row * 136 + colb) = p;
      }
    }
    __syncthreads();
    const int kv_base = n0 - 256;
#pragma unroll
    for (int it = 0; it < 8; ++it) {
      const int chunk = it * 256 + t;       // 2048 chunks of 8 bytes
      const int row = chunk >> 4;
      const int cb  = (chunk & 15) * 8;
      const int gm  = m0 + row;
      if (gm >= M) continue;
      *(int2*)(KV8 + (size_t)gm * 512 + kv_base + cb) = *(const int2*)(cs + row * 136 + cb);
    }
  } else {
#pragma unroll
    for (int mi = 0; mi < 4; mi++) {
      const int row = wm + mi * 16 + l16;
#pragma unroll
      for (int nj = 0; nj < 4; nj++) {
        const int col = wn + nj * 16 + quad * 4;
        short4 o;
        o.x = f2b(acc[mi][nj][0] + bz[nj].x);
        o.y = f2b(acc[mi][nj][1] + bz[nj].y);
        o.z = f2b(acc[mi][nj][2] + bz[nj].z);
        o.w = f2b(acc[mi][nj][3] + bz[nj].w);
        *(short4*)(&smem[row * CLDS + col]) = o;
      }
    }
    __syncthreads();
    const int qs_base = (n_tile < 2) ? n0 : (n0 - 512);   // Q cols or S cols
#pragma unroll
    for (int it = 0; it < 8; ++it) {
      const int chunk = it * 256 + t;       // 2048 chunks of 8 shorts
      const int row = chunk >> 4;
      const int cc  = (chunk & 15) * 8;
      const int gm  = m0 + row;
      if (gm >= M) continue;
      const int4 s4 = *(const int4*)(&smem[row * CLDS + cc]);
      *(int4*)(QS + (size_t)gm * 512 + qs_base + cc) = s4;
    }
  }
}

// ---------- fp8 KV decode ----------
__device__ __forceinline__ void dec_kv(const int2 x, float* k, float* v) {
  f32x2 a = __builtin_amdgcn_cvt_pk_f32_fp8(x.x, false);
  f32x2 b = __builtin_amdgcn_cvt_pk_f32_fp8(x.x, true);
  f32x2 c = __builtin_amdgcn_cvt_pk_f32_fp8(x.y, false);
  f32x2 d = __builtin_amdgcn_cvt_pk_f32_fp8(x.y, true);
  k[0] = a.x; k[1] = a.y; k[2] = b.x; k[3] = b.y;
  v[0] = c.x; v[1] = c.y; v[2] = d.x; v[3] = d.y;
}

// ---------- fused attention: online softmax, fp8 KV, 8-edge MLP ----------
template <typename TOUT>
__device__ __forceinline__ void st1(TOUT* p, float v);
template <> __device__ __forceinline__ void st1<float>(float* p, float v) { *p = v; }
template <> __device__ __forceinline__ void st1<short>(short* p, float v) { *p = f2b(v); }

template <typename TOUT>
__global__ __launch_bounds__(256) void node_attn(
    const int* __restrict__ rowstart, const int* __restrict__ esrc,
    const short* __restrict__ QS, const unsigned char* __restrict__ KV8,
    TOUT* __restrict__ out) {
  const int nid = blockIdx.x * 4 + (threadIdx.x >> 6);
  if (nid >= NN) return;
  const int t  = threadIdx.x & 63;
  const int c0 = t * 4;
  const int r0 = __builtin_amdgcn_readfirstlane(rowstart[nid]);
  const int r1 = __builtin_amdgcn_readfirstlane(rowstart[nid + 1]);
  const float4 q = ld4b(QS + (size_t)nid * 512 + c0);
  const unsigned char* kvb = KV8 + t * 8;
  float m = -INFINITY, denom = 0.f;
  float4 acc = make_float4(0.f, 0.f, 0.f, 0.f);
  int r = r0;
  for (; r + 7 < r1; r += 8) {
    // scalar edge indices -> SGPR base for the gathers; 8 loads in flight
    const int e0 = __builtin_amdgcn_readfirstlane(esrc[r + 0]);
    const int e1 = __builtin_amdgcn_readfirstlane(esrc[r + 1]);
    const int e2 = __builtin_amdgcn_readfirstlane(esrc[r + 2]);
    const int e3 = __builtin_amdgcn_readfirstlane(esrc[r + 3]);
    const int e4 = __builtin_amdgcn_readfirstlane(esrc[r + 4]);
    const int e5 = __builtin_amdgcn_readfirstlane(esrc[r + 5]);
    const int e6 = __builtin_amdgcn_readfirstlane(esrc[r + 6]);
    const int e7 = __builtin_amdgcn_readfirstlane(esrc[r + 7]);
    const int2 x0 = *(const int2*)(kvb + (size_t)e0 * 512);
    const int2 x1 = *(const int2*)(kvb + (size_t)e1 * 512);
    const int2 x2 = *(const int2*)(kvb + (size_t)e2 * 512);
    const int2 x3 = *(const int2*)(kvb + (size_t)e3 * 512);
    const int2 x4 = *(const int2*)(kvb + (size_t)e4 * 512);
    const int2 x5 = *(const int2*)(kvb + (size_t)e5 * 512);
    const int2 x6 = *(const int2*)(kvb + (size_t)e6 * 512);
    const int2 x7 = *(const int2*)(kvb + (size_t)e7 * 512);
    float k0[4], v0[4], k1[4], v1[4], k2[4], v2[4], k3[4], v3[4];
    float k4[4], v4[4], k5[4], v5[4], k6[4], v6[4], k7[4], v7[4];
    dec_kv(x0, k0, v0); dec_kv(x1, k1, v1);
    dec_kv(x2, k2, v2); dec_kv(x3, k3, v3);
    dec_kv(x4, k4, v4); dec_kv(x5, k5, v5);
    dec_kv(x6, k6, v6); dec_kv(x7, k7, v7);
    float d0 = q.x * k0[0] + q.y * k0[1] + q.z * k0[2] + q.w * k0[3];
    float d1 = q.x * k1[0] + q.y * k1[1] + q.z * k1[2] + q.w * k1[3];
    float d2 = q.x * k2[0] + q.y * k2[1] + q.z * k2[2] + q.w * k2[3];
    float d3 = q.x * k3[0] + q.y * k3[1] + q.z * k3[2] + q.w * k3[3];
    float d4 = q.x * k4[0] + q.y * k4[1] + q.z * k4[2] + q.w * k4[3];
    float d5 = q.x * k5[0] + q.y * k5[1] + q.z * k5[2] + q.w * k5[3];
    float d6 = q.x * k6[0] + q.y * k6[1] + q.z * k6[2] + q.w * k6[3];
    float d7 = q.x * k7[0] + q.y * k7[1] + q.z * k7[2] + q.w * k7[3];
#pragma unroll
    for (int off = 1; off <= 8; off <<= 1) {
      d0 += __shfl_xor(d0, off, 16);
      d1 += __shfl_xor(d1, off, 16);
      d2 += __shfl_xor(d2, off, 16);
      d3 += __shfl_xor(d3, off, 16);
      d4 += __shfl_xor(d4, off, 16);
      d5 += __shfl_xor(d5, off, 16);
      d6 += __shfl_xor(d6, off, 16);
      d7 += __shfl_xor(d7, off, 16);
    }
    d0 *= 0.125f; d1 *= 0.125f; d2 *= 0.125f; d3 *= 0.125f;
    d4 *= 0.125f; d5 *= 0.125f; d6 *= 0.125f; d7 *= 0.125f;
    const float t01 = fmaxf(d0, d1), t23 = fmaxf(d2, d3);
    const float t45 = fmaxf(d4, d5), t67 = fmaxf(d6, d7);
    const float nm = fmaxf(fmaxf(m, fmaxf(t01, t23)), fmaxf(t45, t67));
    const float sc  = __expf(m - nm);
    const float ex0 = __expf(d0 - nm);
    const float ex1 = __expf(d1 - nm);
    const float ex2 = __expf(d2 - nm);
    const float ex3 = __expf(d3 - nm);
    const float ex4 = __expf(d4 - nm);
    const float ex5 = __expf(d5 - nm);
    const float ex6 = __expf(d6 - nm);
    const float ex7 = __expf(d7 - nm);
    denom = denom * sc + ((ex0 + ex1) + (ex2 + ex3)) + ((ex4 + ex5) + (ex6 + ex7));
    acc.x = acc.x * sc + ex0 * v0[0] + ex1 * v1[0] + ex2 * v2[0] + ex3 * v3[0]
                       + ex4 * v4[0] + ex5 * v5[0] + ex6 * v6[0] + ex7 * v7[0];
    acc.y = acc.y * sc + ex0 * v0[1] + ex1 * v1[1] + ex2 * v2[1] + ex3 * v3[1]
                       + ex4 * v4[1] + ex5 * v5[1] + ex6 * v6[1] + ex7 * v7[1];
    acc.z = acc.z * sc + ex0 * v0[2] + ex1 * v1[2] + ex2 * v2[2] + ex3 * v3[2]
                       + ex4 * v4[2] + ex5 * v5[2] + ex6 * v6[2] + ex7 * v7[2];
    acc.w = acc.w * sc + ex0 * v0[3] + ex1 * v1[3] + ex2 * v2[3] + ex3 * v3[3]
                       + ex4 * v4[3] + ex5 * v5[3] + ex6 * v6[3] + ex7 * v7[3];
    m = nm;
  }
  for (; r + 3 < r1; r += 4) {
    const int e0 = __builtin_amdgcn_readfirstlane(esrc[r + 0]);
    const int e1 = __builtin_amdgcn_readfirstlane(esrc[r + 1]);
    const int e2 = __builtin_amdgcn_readfirstlane(esrc[r + 2]);
    const int e3 = __builtin_amdgcn_readfirstlane(esrc[r + 3]);
    const int2 x0 = *(const int2*)(kvb + (size_t)e0 * 512);
    const int2 x1 = *(const int2*)(kvb + (size_t)e1 * 512);
    const int2 x2 = *(const int2*)(kvb + (size_t)e2 * 512);
    const int2 x3 = *(const int2*)(kvb + (size_t)e3 * 512);
    float k0[4], v0[4], k1[4], v1[4], k2[4], v2[4], k3[4], v3[4];
    dec_kv(x0, k0, v0); dec_kv(x1, k1, v1);
    dec_kv(x2, k2, v2); dec_kv(x3, k3, v3);
    float d0 = q.x * k0[0] + q.y * k0[1] + q.z * k0[2] + q.w * k0[3];
    float d1 = q.x * k1[0] + q.y * k1[1] + q.z * k1[2] + q.w * k1[3];
    float d2 = q.x * k2[0] + q.y * k2[1] + q.z * k2[2] + q.w * k2[3];
    float d3 = q.x * k3[0] + q.y * k3[1] + q.z * k3[2] + q.w * k3[3];
#pragma unroll
    for (int off = 1; off <= 8; off <<= 1) {
      d0 += __shfl_xor(d0, off, 16);
      d1 += __shfl_xor(d1, off, 16);
      d2 += __shfl_xor(d2, off, 16);
      d3 += __shfl_xor(d3, off, 16);
    }
    d0 *= 0.125f; d1 *= 0.125f; d2 *= 0.125f; d3 *= 0.125f;
    const float nm = fmaxf(fmaxf(m, fmaxf(d0, d1)), fmaxf(d2, d3));
    const float sc = __expf(m - nm);
    const float ex0 = __expf(d0 - nm);
    const float ex1 = __expf(d1 - nm);
    const float ex2 = __expf(d2 - nm);
    const float ex3 = __expf(d3 - nm);
    denom = denom * sc + ex0 + ex1 + ex2 + ex3;
    acc.x = acc.x * sc + ex0 * v0[0] + ex1 * v1[0] + ex2 * v2[0] + ex3 * v3[0];
    acc.y = acc.y * sc + ex0 * v0[1] + ex1 * v1[1] + ex2 * v2[1] + ex3 * v3[1];
    acc.z = acc.z * sc + ex0 * v0[2] + ex1 * v1[2] + ex2 * v2[2] + ex3 * v3[2];
    acc.w = acc.w * sc + ex0 * v0[3] + ex1 * v1[3] + ex2 * v2[3] + ex3 * v3[3];
    m = nm;
  }
  for (; r < r1; r++) {
    const int e0 = __builtin_amdgcn_readfirstlane(esrc[r]);
    const int2 x0 = *(const int2*)(kvb + (size_t)e0 * 512);
    float k0[4], v0[4];
    dec_kv(x0, k0, v0);
    float d0 = q.x * k0[0] + q.y * k0[1] + q.z * k0[2] + q.w * k0[3];
#pragma unroll
    for (int off = 1; off <= 8; off <<= 1) d0 += __shfl_xor(d0, off, 16);
    d0 *= 0.125f;
    const float nm = fmaxf(m, d0);
    const float sc = __expf(m - nm);
    const float ex0 = __expf(d0 - nm);
    denom = denom * sc + ex0;
    acc.x = acc.x * sc + ex0 * v0[0];
    acc.y = acc.y * sc + ex0 * v0[1];
    acc.z = acc.z * sc + ex0 * v0[2];
    acc.w = acc.w * sc + ex0 * v0[3];
    m = nm;
  }
  const float inv = 1.0f / (denom + 1e-16f);
  const float4 sk = ld4b(QS + (size_t)nid * 512 + 256 + c0);
  float o0 = acc.x * inv + sk.x;
  float o1 = acc.y * inv + sk.y;
  float o2 = acc.z * inv + sk.z;
  float o3 = acc.w * inv + sk.w;
  o0 = o0 > 0.f ? o0 : expm1f(o0);
  o1 = o1 > 0.f ? o1 : expm1f(o1);
  o2 = o2 > 0.f ? o2 : expm1f(o2);
  o3 = o3 > 0.f ? o3 : expm1f(o3);
  TOUT* p = out + (size_t)nid * D1 + c0;
  st1<TOUT>(p + 0, o0); st1<TOUT>(p + 1, o1);
  st1<TOUT>(p + 2, o2); st1<TOUT>(p + 3, o3);
}

// ---------- mean-pool partial sums (parallel, run-length atomics) ----------
__global__ __launch_bounds__(256) void pool_k(const float* __restrict__ h,
    const int* __restrict__ batch, float* __restrict__ sums) {
  const int c = threadIdx.x;
  const int n0 = blockIdx.x * 64;
  const int n1 = min(n0 + 64, NN);
  float run = 0.f;
  int curg = -1;
  for (int n = n0; n < n1; n++) {
    int g = batch[n];
    if (g != curg) {
      if (curg >= 0) atomicAdd(&sums[(size_t)curg * D1 + c], run);
      run = 0.f; curg = g;
    }
    run += h[(size_t)n * D1 + c];
  }
  if (curg >= 0) atomicAdd(&sums[(size_t)curg * D1 + c], run);
}

// ---------- classifier + log_softmax (counts from gb) ----------
__global__ __launch_bounds__(640) void head_k(const float* __restrict__ sums,
    const int* __restrict__ gb, const float* __restrict__ Wl,
    const float* __restrict__ bl, float* __restrict__ out) {
  __shared__ float logits[NG][NOUT];
  const int t = threadIdx.x;
  if (t < NG * NOUT) {
    int g = t / NOUT, o = t % NOUT;
    float inv = 1.0f / fmaxf((float)(gb[g + 1] - gb[g]), 1.0f);
    float acc = 0.f;
    for (int k = 0; k < D1; k++) acc += sums[(size_t)g * D1 + k] * Wl[k * NOUT + o];
    logits[g][o] = acc * inv + bl[o];
  }
  __syncthreads();
  if (t < NG) {
    float mx = -INFINITY;
#pragma unroll
    for (int o = 0; o < NOUT; o++) mx = fmaxf(mx, logits[t][o]);
    float s = 0.f;
#pragma unroll
    for (int o = 0; o < NOUT; o++) s += __expf(logits[t][o] - mx);
    float lse = mx + logf(s);
#pragma unroll
    for (int o = 0; o < NOUT; o++) out[t * NOUT + o] = logits[t][o] - lse;
  }
}

// ---------------------------------------------------------------------------
extern "C" void kernel_launch(void* const* d_in, const int* in_sizes, int n_in,
                              void* d_out, int out_size, void* d_ws, size_t ws_size,
                              hipStream_t stream) {
  const float* x   = (const float*)d_in[0];
  const int* ei    = (const int*)d_in[1];
  const int* batch = (const int*)d_in[2];
  const float* Wq1 = (const float*)d_in[3];  const float* bq1 = (const float*)d_in[4];
  const float* Wk1 = (const float*)d_in[5];  const float* bk1 = (const float*)d_in[6];
  const float* Wv1 = (const float*)d_in[7];  const float* bv1 = (const float*)d_in[8];
  const float* Ws1 = (const float*)d_in[9];  const float* bs1 = (const float*)d_in[10];
  const float* Wq2 = (const float*)d_in[11]; const float* bq2 = (const float*)d_in[12];
  const float* Wk2 = (const float*)d_in[13]; const float* bk2 = (const float*)d_in[14];
  const float* Wv2 = (const float*)d_in[15]; const float* bv2 = (const float*)d_in[16];
  const float* Ws2 = (const float*)d_in[17]; const float* bs2 = (const float*)d_in[18];
  const float* Wl  = (const float*)d_in[19]; const float* bl  = (const float*)d_in[20];

  const int* srcIdx = ei;          // edge_index[0] (source j)
  const int* dstIdx = ei + NE;     // edge_index[1] (target i)

  // -------- workspace layout --------
  float* ws = (float*)d_ws;
  const size_t SZ_NODE = (size_t)NN * D1;       // 12.8M elems
  float* H2f  = ws;                              // NN*D1 fp32
  float* sums = ws + SZ_NODE;                    // NG*D1
  float* bc1  = sums + (size_t)NG * D1;          // 1024
  float* bc2  = bc1 + D4;                        // 1024
  short* Xb   = (short*)(bc2 + D4);              // NN*INC
  short* H1b  = Xb + (size_t)NN * INC;           // NN*D1
  short* QS   = H1b + SZ_NODE;                   // NN*512 bf16 (Q|S)
  short* Wtc1 = QS + (size_t)NN * 512;           // 1024*128
  short* Wtc2 = Wtc1 + (size_t)D4 * INC;         // 1024*256
  unsigned char* KV8 = (unsigned char*)(Wtc2 + (size_t)D4 * D1);  // NN*512 fp8
  int* ip      = (int*)(KV8 + (size_t)NN * 512);
  int* deg     = ip;                 // NN
  int* partial = deg + NN;           // 256
  int* rowstart= partial + 256;      // NN+1
  int* cursor  = rowstart + NN + 1;  // NN
  int* esrc    = cursor + NN;        // NE
  int* gb      = esrc + NE;          // NG+1

  const int mtiles = (NN + 127) / 128;           // 391
  const dim3 gemmGrid(64, (mtiles + 7) / 8);     // 64 x 49 swizzled
  const int edgeBlocks = (NE + 255) / 256;
  const int aggBlocks  = (NN + 3) / 4;
  const int cvtBlocks  = CVT_XB + CVT_W1B + CVT_W2B + CVT_BB + CVT_DB + CVT_SB;

  // ======== Converts + zeroing (one kernel) ========
  cvt_all_k<<<cvtBlocks, 256, 0, stream>>>(x, Xb,
      Wq1, Wk1, Wv1, Ws1, Wq2, Wk2, Wv2, Ws2, Wtc1, Wtc2,
      bq1, bk1, bv1, bs1, bq2, bk2, bv2, bs2, bc1, bc2, deg, sums);

  // ======== CSR build + graph bounds ========
  deg_count<<<edgeBlocks, 256, 0, stream>>>(dstIdx, deg);
  scan1<<<NB_SCAN + 1, 256, 0, stream>>>(deg, partial, batch, gb);
  scan3<<<NB_SCAN, 256, 0, stream>>>(deg, partial, rowstart, cursor);
  scatter_k<<<edgeBlocks, 256, 0, stream>>>(srcIdx, dstIdx, cursor, esrc);

  // ======== Layer 1 ========
  gemm_mfma<<<gemmGrid, 256, 0, stream>>>(Xb, Wtc1, bc1, QS, KV8, NN, INC);
  node_attn<short><<<aggBlocks, 256, 0, stream>>>(rowstart, esrc, QS, KV8, H1b);

  // ======== Layer 2 ========
  gemm_mfma<<<gemmGrid, 256, 0, stream>>>(H1b, Wtc2, bc2, QS, KV8, NN, D1);
  node_attn<float><<<aggBlocks, 256, 0, stream>>>(rowstart, esrc, QS, KV8, H2f);

  // ======== Pool + head ========
  pool_k<<<(NN + 63) / 64, 256, 0, stream>>>(H2f, batch, sums);
  head_k<<<1, 640, 0, stream>>>(sums, gb, Wl, bl, (float*)d_out);
}

// Round 4
// 357.622 us; speedup vs baseline: 1.1132x; 1.0172x over previous
//
#include <hip/hip_runtime.h>
#include <math.h>

constexpr int NN   = 50000;   // nodes
constexpr int NE   = 400000;  // edges
constexpr int INC  = 128;     // in channels
constexpr int NH   = 4;       // heads
constexpr int D1   = 256;     // NH*HIDC
constexpr int D4   = 1024;    // 4*D1 fused QKVS logical cols
constexpr int NOUT = 10;      // classes
constexpr int NG   = 64;      // graphs
constexpr int NB_SCAN = (NN + 255) / 256;   // 196 scan blocks

// GEMM output split per node:
//   QS[node][512] bf16 : cols 0..255 = Q, cols 256..511 = S
//   KV8[node][512] fp8 : byte j -> group g=j>>3, off=j&7: off<4 -> K ch 4g+off,
//                                                        off>=4 -> V ch 4g+(off-4)
// Lane t of node_attn reads 8 B at node*512 + t*8 = [K c0..c0+3 | V c0..c0+3].

typedef __attribute__((ext_vector_type(8))) short bf16x8;   // MFMA A/B frag
typedef __attribute__((ext_vector_type(4))) float f32x4;    // MFMA C/D frag
typedef __attribute__((ext_vector_type(2))) float f32x2;

// ---------- bf16 helpers ----------
__device__ __forceinline__ short f2b(float f) {
  union { float f; unsigned int i; } v; v.f = f;
  unsigned int x = v.i;
  return (short)((x + 0x7FFFu + ((x >> 16) & 1u)) >> 16);
}
__device__ __forceinline__ float b2f(short u) {
  union { unsigned int i; float f; } v; v.i = ((unsigned int)(unsigned short)u) << 16;
  return v.f;
}
__device__ __forceinline__ float4 ld4b(const short* p) {
  short4 u = *(const short4*)p;
  return make_float4(b2f(u.x), b2f(u.y), b2f(u.z), b2f(u.w));
}
// pack 4 floats -> 4 fp8 e4m3 bytes (HW convert)
__device__ __forceinline__ int pk_fp8x4(float a, float b, float c, float d) {
  int v = __builtin_amdgcn_cvt_pk_fp8_f32(a, b, 0, false);
  v = __builtin_amdgcn_cvt_pk_fp8_f32(c, d, v, true);
  return v;
}

// ---------- async global->LDS 16B ----------
__device__ __forceinline__ void gld_lds16(const short* g, short* l) {
  __builtin_amdgcn_global_load_lds(
      (const __attribute__((address_space(1))) unsigned int*)g,
      (__attribute__((address_space(3))) unsigned int*)l, 16, 0, 0);
}

// ---------- fused converts + zeroing (one dispatch) ----------
constexpr int CVT_XB  = (NN * INC / 4 + 255) / 256;   // 6250 blocks
constexpr int CVT_W1B = (4 * D1 * INC + 255) / 256;   // 512
constexpr int CVT_W2B = (4 * D1 * D1 + 255) / 256;    // 1024
constexpr int CVT_BB  = 8;                            // bias blocks
constexpr int CVT_DB  = (NN + 255) / 256;             // deg zero (196)
constexpr int CVT_SB  = (NG * D1 + 255) / 256;        // sums zero (64)

__device__ __forceinline__ void wt_one(const float* Wq, const float* Wk,
    const float* Wv, const float* Ws, short* Wt, int kbits, int i) {
  int K = 1 << kbits;
  int seg = i >> (kbits + 8);               // 0=Q 1=K 2=V 3=S
  int idx = i & ((D1 << kbits) - 1);
  int n = idx >> kbits, k = idx & (K - 1);
  const float* W = (seg == 0) ? Wq : (seg == 1) ? Wk : (seg == 2) ? Wv : Ws;
  int row;
  if (seg == 0)      row = n;
  else if (seg == 3) row = 768 + n;
  else               row = 256 + (n >> 2) * 8 + ((seg == 2) ? 4 : 0) + (n & 3);
  Wt[(size_t)row * K + k] = f2b(W[(size_t)k * D1 + n]);
}

__global__ void cvt_all_k(const float* __restrict__ x, short* __restrict__ Xb,
    const float* __restrict__ Wq1, const float* __restrict__ Wk1,
    const float* __restrict__ Wv1, const float* __restrict__ Ws1,
    const float* __restrict__ Wq2, const float* __restrict__ Wk2,
    const float* __restrict__ Wv2, const float* __restrict__ Ws2,
    short* __restrict__ Wtc1, short* __restrict__ Wtc2,
    const float* __restrict__ bq1, const float* __restrict__ bk1,
    const float* __restrict__ bv1, const float* __restrict__ bs1,
    const float* __restrict__ bq2, const float* __restrict__ bk2,
    const float* __restrict__ bv2, const float* __restrict__ bs2,
    float* __restrict__ bc1, float* __restrict__ bc2,
    int* __restrict__ deg, float* __restrict__ sums) {
  const int b = blockIdx.x;
  const int t = threadIdx.x;
  if (b < CVT_XB) {                               // x -> bf16 (4/thread)
    int i = (b * 256 + t) * 4;
    if (i >= NN * INC) return;
    float4 v = *(const float4*)(x + i);
    short4 o; o.x = f2b(v.x); o.y = f2b(v.y); o.z = f2b(v.z); o.w = f2b(v.w);
    *(short4*)(Xb + i) = o;
  } else if (b < CVT_XB + CVT_W1B) {              // layer-1 weights
    int i = (b - CVT_XB) * 256 + t;
    if (i < 4 * D1 * INC) wt_one(Wq1, Wk1, Wv1, Ws1, Wtc1, 7, i);
  } else if (b < CVT_XB + CVT_W1B + CVT_W2B) {    // layer-2 weights
    int i = (b - CVT_XB - CVT_W1B) * 256 + t;
    if (i < 4 * D1 * D1) wt_one(Wq2, Wk2, Wv2, Ws2, Wtc2, 8, i);
  } else if (b < CVT_XB + CVT_W1B + CVT_W2B + CVT_BB) {  // bias concat
    int i = (b - CVT_XB - CVT_W1B - CVT_W2B) * 256 + t;
    if (i >= 2 * D4) return;
    int row = i & (D4 - 1);
    const float* bq = (i < D4) ? bq1 : bq2;
    const float* bk = (i < D4) ? bk1 : bk2;
    const float* bv = (i < D4) ? bv1 : bv2;
    const float* bs = (i < D4) ? bs1 : bs2;
    float v;
    if (row < 256) v = bq[row];
    else if (row < 768) {
      int j = row - 256, grp = j >> 3, off = j & 7;
      int ch = grp * 4 + (off & 3);
      v = (off < 4) ? bk[ch] : bv[ch];
    } else v = bs[row - 768];
    ((i < D4) ? bc1 : bc2)[row] = v;
  } else if (b < CVT_XB + CVT_W1B + CVT_W2B + CVT_BB + CVT_DB) {  // deg = 0
    int i = (b - CVT_XB - CVT_W1B - CVT_W2B - CVT_BB) * 256 + t;
    if (i < NN) deg[i] = 0;
  } else {                                        // sums = 0
    int i = (b - CVT_XB - CVT_W1B - CVT_W2B - CVT_BB - CVT_DB) * 256 + t;
    if (i < NG * D1) sums[i] = 0.f;
  }
}

// ---------- CSR build ----------
__global__ void deg_count(const int* __restrict__ dst, int* __restrict__ deg) {
  int e = blockIdx.x * 256 + threadIdx.x;
  if (e < NE) atomicAdd(&deg[dst[e]], 1);
}
// block partial sums; extra block NB_SCAN does graph bounds (binary search)
__global__ __launch_bounds__(256) void scan1(const int* __restrict__ deg,
    int* __restrict__ partial, const int* __restrict__ batch, int* __restrict__ gb) {
  if (blockIdx.x == NB_SCAN) {
    int g = threadIdx.x;
    if (g > NG) return;
    int lo = 0, hi = NN;
    while (lo < hi) {
      int mid = (lo + hi) >> 1;
      if (batch[mid] < g) lo = mid + 1; else hi = mid;
    }
    gb[g] = lo;
    return;
  }
  __shared__ int sh[256];
  int t = threadIdx.x, i = blockIdx.x * 256 + t;
  sh[t] = (i < NN) ? deg[i] : 0;
  __syncthreads();
  for (int off = 128; off > 0; off >>= 1) {
    if (t < off) sh[t] += sh[t + off];
    __syncthreads();
  }
  if (t == 0) partial[blockIdx.x] = sh[0];
}
__global__ __launch_bounds__(256) void scan3(const int* __restrict__ deg,
    const int* __restrict__ partial, int* __restrict__ rowstart,
    int* __restrict__ cursor) {
  __shared__ int sh[256];
  __shared__ int base_s;
  const int t = threadIdx.x;
  int pv = (t < NB_SCAN) ? partial[t] : 0;
  sh[t] = pv;
  __syncthreads();
  for (int off = 1; off < 256; off <<= 1) {
    int o = (t >= off) ? sh[t - off] : 0;
    __syncthreads();
    sh[t] += o;
    __syncthreads();
  }
  if (t == 0) base_s = (blockIdx.x == 0) ? 0 : sh[blockIdx.x - 1];
  __syncthreads();
  const int base = base_s;
  __syncthreads();
  int i = blockIdx.x * 256 + t;
  int v = (i < NN) ? deg[i] : 0;
  sh[t] = v;
  __syncthreads();
  for (int off = 1; off < 256; off <<= 1) {
    int o = (t >= off) ? sh[t - off] : 0;
    __syncthreads();
    sh[t] += o;
    __syncthreads();
  }
  int excl = sh[t] - v + base;
  if (i <= NN) rowstart[i] = excl;
  if (i < NN)  cursor[i]   = excl;
}
__global__ void scatter_k(const int* __restrict__ src, const int* __restrict__ dst,
    int* __restrict__ cursor, int* __restrict__ esrc) {
  int e = blockIdx.x * 256 + threadIdx.x;
  if (e >= NE) return;
  int d = dst[e];
  int pos = atomicAdd(&cursor[d], 1);
  esrc[pos] = src[e];
}

// ---------- MFMA GEMM: [QS bf16 | KV8 fp8] = Xb[M,K] @ Wt[1024,K]^T + bias ----
// Swapped-operand MFMA (C^T fragments): lane holds 4 CONSECUTIVE output cols
// (col = quad*4+r, row = l16). XOR-swizzled LDS staging (conflict-free K-loop,
// verified round 2: SQ_LDS_BANK_CONFLICT 3.6M -> 0). Double-buffered K-step=32
// pipeline, ONE barrier per step. Epilogue: LDS-staged C tile + coalesced
// copy-out (verified round 3: gemm 67 -> <49 us).
constexpr int CLDS = 136;   // C-tile LDS stride in shorts

__global__ __launch_bounds__(256) void gemm_mfma(
    const short* __restrict__ Xb, const short* __restrict__ Wt,
    const float* __restrict__ bias, short* __restrict__ QS,
    unsigned char* __restrict__ KV8, int M, int K) {
  __shared__ short smem[128 * CLDS];   // 34816 B; staging aliases first 32 KB
  const int bx = blockIdx.x;                 // 0..63
  const int by = blockIdx.y;
  const int m_tile = (bx & 7) + (by << 3);   // XCD swizzle
  const int n_tile = bx >> 3;                // 0..7
  const int m0 = m_tile * 128;
  if (m0 >= M) return;
  const int n0 = n_tile * 128;

  const int t    = threadIdx.x;
  const int lane = t & 63;
  const int wv   = t >> 6;
  const int wm   = (wv >> 1) * 64;
  const int wn   = (wv & 1) * 64;
  const int quad = lane >> 4;
  const int l16  = lane & 15;
  const int lrow = lane >> 2;
  const int lseg = lane & 3;

  const int swz_w = (lseg ^ ((lrow >> 1) & 3)) * 8;   // staging source swizzle
  const int swz_r = (quad ^ ((l16 >> 1) & 3)) * 8;    // fragment read swizzle

  // buffers (shorts): A0 [0,4096) B0 [4096,8192) A1 [8192,12288) B1 [12288,16384)
  f32x4 acc[4][4] = {};

  // prologue: stage tile k0=0 into buffer 0
  {
#pragma unroll
    for (int j = 0; j < 2; ++j) {
      const int rb = (wv * 2 + j) * 16;      // 16 rows per issue per matrix
      int gm = m0 + rb + lrow;
      gm = gm < M ? gm : M - 1;
      gld_lds16(Xb + (size_t)gm * K + swz_w,              &smem[rb * 32]);
      gld_lds16(Wt + (size_t)(n0 + rb + lrow) * K + swz_w, &smem[4096 + rb * 32]);
    }
  }
  __syncthreads();

  int cur = 0;
  for (int k0 = 0; k0 < K; k0 += 32) {
    // prefetch next K-tile into the other buffer (overlaps with compute)
    if (k0 + 32 < K) {
      short* An = &smem[(cur ^ 1) * 8192];
      short* Bn = &smem[(cur ^ 1) * 8192 + 4096];
#pragma unroll
      for (int j = 0; j < 2; ++j) {
        const int rb = (wv * 2 + j) * 16;
        int gm = m0 + rb + lrow;
        gm = gm < M ? gm : M - 1;
        gld_lds16(Xb + (size_t)gm * K + k0 + 32 + swz_w,              &An[rb * 32]);
        gld_lds16(Wt + (size_t)(n0 + rb + lrow) * K + k0 + 32 + swz_w, &Bn[rb * 32]);
      }
    }
    // compute current buffer
    {
      const short* Ac = &smem[cur * 8192];
      const short* Bc = &smem[cur * 8192 + 4096];
      bf16x8 a[4], b[4];
#pragma unroll
      for (int mi = 0; mi < 4; mi++)
        a[mi] = *(const bf16x8*)(&Ac[(wm + mi * 16 + l16) * 32 + swz_r]);
#pragma unroll
      for (int nj = 0; nj < 4; nj++)
        b[nj] = *(const bf16x8*)(&Bc[(wn + nj * 16 + l16) * 32 + swz_r]);
#pragma unroll
      for (int mi = 0; mi < 4; mi++)
#pragma unroll
        for (int nj = 0; nj < 4; nj++)
          acc[mi][nj] = __builtin_amdgcn_mfma_f32_16x16x32_bf16(b[nj], a[mi], acc[mi][nj], 0, 0, 0);
    }
    __syncthreads();   // waits prefetch (vmcnt) + guards buffer reuse
    cur ^= 1;
  }

  // ---- epilogue: bias + pack in-register, stage in LDS, coalesced copy-out --
  const bool isKV = (n_tile >= 2) && (n_tile <= 5);
  float4 bz[4];
#pragma unroll
  for (int nj = 0; nj < 4; nj++)
    bz[nj] = *(const float4*)(bias + n0 + wn + nj * 16 + quad * 4);

  if (isKV) {
    unsigned char* cs = (unsigned char*)smem;      // [128][136] bytes
#pragma unroll
    for (int mi = 0; mi < 4; mi++) {
      const int row = wm + mi * 16 + l16;
#pragma unroll
      for (int nj = 0; nj < 4; nj++) {
        const int colb = wn + nj * 16 + quad * 4;
        const int p = pk_fp8x4(acc[mi][nj][0] + bz[nj].x, acc[mi][nj][1] + bz[nj].y,
                               acc[mi][nj][2] + bz[nj].z, acc[mi][nj][3] + bz[nj].w);
        *(int*)(cs + row * 136 + colb) = p;
      }
    }
    __syncthreads();
    const int kv_base = n0 - 256;
#pragma unroll
    for (int it = 0; it < 8; ++it) {
      const int chunk = it * 256 + t;       // 2048 chunks of 8 bytes
      const int row = chunk >> 4;
      const int cb  = (chunk & 15) * 8;
      const int gm  = m0 + row;
      if (gm >= M) continue;
      *(int2*)(KV8 + (size_t)gm * 512 + kv_base + cb) = *(const int2*)(cs + row * 136 + cb);
    }
  } else {
#pragma unroll
    for (int mi = 0; mi < 4; mi++) {
      const int row = wm + mi * 16 + l16;
#pragma unroll
      for (int nj = 0; nj < 4; nj++) {
        const int col = wn + nj * 16 + quad * 4;
        short4 o;
        o.x = f2b(acc[mi][nj][0] + bz[nj].x);
        o.y = f2b(acc[mi][nj][1] + bz[nj].y);
        o.z = f2b(acc[mi][nj][2] + bz[nj].z);
        o.w = f2b(acc[mi][nj][3] + bz[nj].w);
        *(short4*)(&smem[row * CLDS + col]) = o;
      }
    }
    __syncthreads();
    const int qs_base = (n_tile < 2) ? n0 : (n0 - 512);   // Q cols or S cols
#pragma unroll
    for (int it = 0; it < 8; ++it) {
      const int chunk = it * 256 + t;       // 2048 chunks of 8 shorts
      const int row = chunk >> 4;
      const int cc  = (chunk & 15) * 8;
      const int gm  = m0 + row;
      if (gm >= M) continue;
      const int4 s4 = *(const int4*)(&smem[row * CLDS + cc]);
      *(int4*)(QS + (size_t)gm * 512 + qs_base + cc) = s4;
    }
  }
}

// ---------- fp8 KV decode (keep pairs packed for v_pk_* math) ----------
__device__ __forceinline__ f32x2 cvt_lo(int x) { return __builtin_amdgcn_cvt_pk_f32_fp8(x, false); }
__device__ __forceinline__ f32x2 cvt_hi(int x) { return __builtin_amdgcn_cvt_pk_f32_fp8(x, true); }

// ---------- DPP rotate-reduce over 16 lanes (pure VALU, no DS pipe) --------
// row_ror:N within a 16-lane row; rotations by 1,2,4,8 fully sum a
// commutative op across the row (each lane ends with the row total).
template <int CTRL>
__device__ __forceinline__ float ror_add(float x) {
  int y = __builtin_amdgcn_update_dpp(0, __float_as_int(x), CTRL, 0xF, 0xF, true);
  return x + __int_as_float(y);
}
__device__ __forceinline__ float red16(float x) {
  x = ror_add<0x121>(x);   // row_ror:1
  x = ror_add<0x122>(x);   // row_ror:2
  x = ror_add<0x124>(x);   // row_ror:4
  x = ror_add<0x128>(x);   // row_ror:8
  return x;
}

// score scale: 1/sqrt(64) folded with log2(e) -> softmax runs in exp2 domain
#define SC2 (0.125f * 1.44269504088896341f)

// per-edge: decode K/V pairs, packed dot with Q, 16-lane reduce -> raw score
__device__ __forceinline__ float edge_score(const int2 x, f32x2 q01, f32x2 q23,
                                            f32x2& vv01, f32x2& vv23) {
  f32x2 kk01 = cvt_lo(x.x), kk23 = cvt_hi(x.x);
  vv01 = cvt_lo(x.y); vv23 = cvt_hi(x.y);
  f32x2 dd = q01 * kk01;
  dd += q23 * kk23;
  return red16(dd.x + dd.y);
}

// ---------- fused attention: online softmax (exp2 domain), fp8 KV ----------
template <typename TOUT>
__device__ __forceinline__ void st1(TOUT* p, float v);
template <> __device__ __forceinline__ void st1<float>(float* p, float v) { *p = v; }
template <> __device__ __forceinline__ void st1<short>(short* p, float v) { *p = f2b(v); }

template <typename TOUT>
__global__ __launch_bounds__(256) void node_attn(
    const int* __restrict__ rowstart, const int* __restrict__ esrc,
    const short* __restrict__ QS, const unsigned char* __restrict__ KV8,
    TOUT* __restrict__ out) {
  const int nid = blockIdx.x * 4 + (threadIdx.x >> 6);
  if (nid >= NN) return;
  const int t  = threadIdx.x & 63;
  const int c0 = t * 4;
  const int r0 = __builtin_amdgcn_readfirstlane(rowstart[nid]);
  const int r1 = __builtin_amdgcn_readfirstlane(rowstart[nid + 1]);
  const short4 qu = *(const short4*)(QS + (size_t)nid * 512 + c0);
  const f32x2 q01 = {b2f(qu.x), b2f(qu.y)};
  const f32x2 q23 = {b2f(qu.z), b2f(qu.w)};
  const unsigned char* kvb = KV8 + t * 8;
  float m = -INFINITY, denom = 0.f;
  f32x2 a01 = {0.f, 0.f}, a23 = {0.f, 0.f};
  int r = r0;
  for (; r + 7 < r1; r += 8) {
    const int e0 = __builtin_amdgcn_readfirstlane(esrc[r + 0]);
    const int e1 = __builtin_amdgcn_readfirstlane(esrc[r + 1]);
    const int e2 = __builtin_amdgcn_readfirstlane(esrc[r + 2]);
    const int e3 = __builtin_amdgcn_readfirstlane(esrc[r + 3]);
    const int e4 = __builtin_amdgcn_readfirstlane(esrc[r + 4]);
    const int e5 = __builtin_amdgcn_readfirstlane(esrc[r + 5]);
    const int e6 = __builtin_amdgcn_readfirstlane(esrc[r + 6]);
    const int e7 = __builtin_amdgcn_readfirstlane(esrc[r + 7]);
    const int2 x0 = *(const int2*)(kvb + (size_t)e0 * 512);
    const int2 x1 = *(const int2*)(kvb + (size_t)e1 * 512);
    const int2 x2 = *(const int2*)(kvb + (size_t)e2 * 512);
    const int2 x3 = *(const int2*)(kvb + (size_t)e3 * 512);
    const int2 x4 = *(const int2*)(kvb + (size_t)e4 * 512);
    const int2 x5 = *(const int2*)(kvb + (size_t)e5 * 512);
    const int2 x6 = *(const int2*)(kvb + (size_t)e6 * 512);
    const int2 x7 = *(const int2*)(kvb + (size_t)e7 * 512);
    f32x2 v01_0, v23_0, v01_1, v23_1, v01_2, v23_2, v01_3, v23_3;
    f32x2 v01_4, v23_4, v01_5, v23_5, v01_6, v23_6, v01_7, v23_7;
    const float s0 = edge_score(x0, q01, q23, v01_0, v23_0) * SC2;
    const float s1 = edge_score(x1, q01, q23, v01_1, v23_1) * SC2;
    const float s2 = edge_score(x2, q01, q23, v01_2, v23_2) * SC2;
    const float s3 = edge_score(x3, q01, q23, v01_3, v23_3) * SC2;
    const float s4 = edge_score(x4, q01, q23, v01_4, v23_4) * SC2;
    const float s5 = edge_score(x5, q01, q23, v01_5, v23_5) * SC2;
    const float s6 = edge_score(x6, q01, q23, v01_6, v23_6) * SC2;
    const float s7 = edge_score(x7, q01, q23, v01_7, v23_7) * SC2;
    const float t01 = fmaxf(s0, s1), t23 = fmaxf(s2, s3);
    const float t45 = fmaxf(s4, s5), t67 = fmaxf(s6, s7);
    const float nm = fmaxf(fmaxf(m, fmaxf(t01, t23)), fmaxf(t45, t67));
    const float sc  = exp2f(m - nm);
    const float ex0 = exp2f(s0 - nm);
    const float ex1 = exp2f(s1 - nm);
    const float ex2 = exp2f(s2 - nm);
    const float ex3 = exp2f(s3 - nm);
    const float ex4 = exp2f(s4 - nm);
    const float ex5 = exp2f(s5 - nm);
    const float ex6 = exp2f(s6 - nm);
    const float ex7 = exp2f(s7 - nm);
    denom = denom * sc + ((ex0 + ex1) + (ex2 + ex3)) + ((ex4 + ex5) + (ex6 + ex7));
    const f32x2 scv = {sc, sc};
    a01 = a01 * scv; a23 = a23 * scv;
    a01 += f32x2{ex0, ex0} * v01_0; a23 += f32x2{ex0, ex0} * v23_0;
    a01 += f32x2{ex1, ex1} * v01_1; a23 += f32x2{ex1, ex1} * v23_1;
    a01 += f32x2{ex2, ex2} * v01_2; a23 += f32x2{ex2, ex2} * v23_2;
    a01 += f32x2{ex3, ex3} * v01_3; a23 += f32x2{ex3, ex3} * v23_3;
    a01 += f32x2{ex4, ex4} * v01_4; a23 += f32x2{ex4, ex4} * v23_4;
    a01 += f32x2{ex5, ex5} * v01_5; a23 += f32x2{ex5, ex5} * v23_5;
    a01 += f32x2{ex6, ex6} * v01_6; a23 += f32x2{ex6, ex6} * v23_6;
    a01 += f32x2{ex7, ex7} * v01_7; a23 += f32x2{ex7, ex7} * v23_7;
    m = nm;
  }
  for (; r + 3 < r1; r += 4) {
    const int e0 = __builtin_amdgcn_readfirstlane(esrc[r + 0]);
    const int e1 = __builtin_amdgcn_readfirstlane(esrc[r + 1]);
    const int e2 = __builtin_amdgcn_readfirstlane(esrc[r + 2]);
    const int e3 = __builtin_amdgcn_readfirstlane(esrc[r + 3]);
    const int2 x0 = *(const int2*)(kvb + (size_t)e0 * 512);
    const int2 x1 = *(const int2*)(kvb + (size_t)e1 * 512);
    const int2 x2 = *(const int2*)(kvb + (size_t)e2 * 512);
    const int2 x3 = *(const int2*)(kvb + (size_t)e3 * 512);
    f32x2 v01_0, v23_0, v01_1, v23_1, v01_2, v23_2, v01_3, v23_3;
    const float s0 = edge_score(x0, q01, q23, v01_0, v23_0) * SC2;
    const float s1 = edge_score(x1, q01, q23, v01_1, v23_1) * SC2;
    const float s2 = edge_score(x2, q01, q23, v01_2, v23_2) * SC2;
    const float s3 = edge_score(x3, q01, q23, v01_3, v23_3) * SC2;
    const float nm = fmaxf(fmaxf(m, fmaxf(s0, s1)), fmaxf(s2, s3));
    const float sc  = exp2f(m - nm);
    const float ex0 = exp2f(s0 - nm);
    const float ex1 = exp2f(s1 - nm);
    const float ex2 = exp2f(s2 - nm);
    const float ex3 = exp2f(s3 - nm);
    denom = denom * sc + ex0 + ex1 + ex2 + ex3;
    const f32x2 scv = {sc, sc};
    a01 = a01 * scv; a23 = a23 * scv;
    a01 += f32x2{ex0, ex0} * v01_0; a23 += f32x2{ex0, ex0} * v23_0;
    a01 += f32x2{ex1, ex1} * v01_1; a23 += f32x2{ex1, ex1} * v23_1;
    a01 += f32x2{ex2, ex2} * v01_2; a23 += f32x2{ex2, ex2} * v23_2;
    a01 += f32x2{ex3, ex3} * v01_3; a23 += f32x2{ex3, ex3} * v23_3;
    m = nm;
  }
  for (; r < r1; r++) {
    const int e0 = __builtin_amdgcn_readfirstlane(esrc[r]);
    const int2 x0 = *(const int2*)(kvb + (size_t)e0 * 512);
    f32x2 v01_0, v23_0;
    const float s0 = edge_score(x0, q01, q23, v01_0, v23_0) * SC2;
    const float nm = fmaxf(m, s0);
    const float sc  = exp2f(m - nm);
    const float ex0 = exp2f(s0 - nm);
    denom = denom * sc + ex0;
    const f32x2 scv = {sc, sc};
    a01 = a01 * scv; a23 = a23 * scv;
    a01 += f32x2{ex0, ex0} * v01_0; a23 += f32x2{ex0, ex0} * v23_0;
    m = nm;
  }
  const float inv = 1.0f / (denom + 1e-16f);
  const float4 sk = ld4b(QS + (size_t)nid * 512 + 256 + c0);
  float o0 = a01.x * inv + sk.x;
  float o1 = a01.y * inv + sk.y;
  float o2 = a23.x * inv + sk.z;
  float o3 = a23.y * inv + sk.w;
  o0 = o0 > 0.f ? o0 : expm1f(o0);
  o1 = o1 > 0.f ? o1 : expm1f(o1);
  o2 = o2 > 0.f ? o2 : expm1f(o2);
  o3 = o3 > 0.f ? o3 : expm1f(o3);
  TOUT* p = out + (size_t)nid * D1 + c0;
  st1<TOUT>(p + 0, o0); st1<TOUT>(p + 1, o1);
  st1<TOUT>(p + 2, o2); st1<TOUT>(p + 3, o3);
}

// ---------- mean-pool partial sums (parallel, run-length atomics) ----------
__global__ __launch_bounds__(256) void pool_k(const float* __restrict__ h,
    const int* __restrict__ batch, float* __restrict__ sums) {
  const int c = threadIdx.x;
  const int n0 = blockIdx.x * 64;
  const int n1 = min(n0 + 64, NN);
  float run = 0.f;
  int curg = -1;
  for (int n = n0; n < n1; n++) {
    int g = batch[n];
    if (g != curg) {
      if (curg >= 0) atomicAdd(&sums[(size_t)curg * D1 + c], run);
      run = 0.f; curg = g;
    }
    run += h[(size_t)n * D1 + c];
  }
  if (curg >= 0) atomicAdd(&sums[(size_t)curg * D1 + c], run);
}

// ---------- classifier + log_softmax (counts from gb) ----------
__global__ __launch_bounds__(640) void head_k(const float* __restrict__ sums,
    const int* __restrict__ gb, const float* __restrict__ Wl,
    const float* __restrict__ bl, float* __restrict__ out) {
  __shared__ float logits[NG][NOUT];
  const int t = threadIdx.x;
  if (t < NG * NOUT) {
    int g = t / NOUT, o = t % NOUT;
    float inv = 1.0f / fmaxf((float)(gb[g + 1] - gb[g]), 1.0f);
    float acc = 0.f;
    for (int k = 0; k < D1; k++) acc += sums[(size_t)g * D1 + k] * Wl[k * NOUT + o];
    logits[g][o] = acc * inv + bl[o];
  }
  __syncthreads();
  if (t < NG) {
    float mx = -INFINITY;
#pragma unroll
    for (int o = 0; o < NOUT; o++) mx = fmaxf(mx, logits[t][o]);
    float s = 0.f;
#pragma unroll
    for (int o = 0; o < NOUT; o++) s += __expf(logits[t][o] - mx);
    float lse = mx + logf(s);
#pragma unroll
    for (int o = 0; o < NOUT; o++) out[t * NOUT + o] = logits[t][o] - lse;
  }
}

// ---------------------------------------------------------------------------
extern "C" void kernel_launch(void* const* d_in, const int* in_sizes, int n_in,
                              void* d_out, int out_size, void* d_ws, size_t ws_size,
                              hipStream_t stream) {
  const float* x   = (const float*)d_in[0];
  const int* ei    = (const int*)d_in[1];
  const int* batch = (const int*)d_in[2];
  const float* Wq1 = (const float*)d_in[3];  const float* bq1 = (const float*)d_in[4];
  const float* Wk1 = (const float*)d_in[5];  const float* bk1 = (const float*)d_in[6];
  const float* Wv1 = (const float*)d_in[7];  const float* bv1 = (const float*)d_in[8];
  const float* Ws1 = (const float*)d_in[9];  const float* bs1 = (const float*)d_in[10];
  const float* Wq2 = (const float*)d_in[11]; const float* bq2 = (const float*)d_in[12];
  const float* Wk2 = (const float*)d_in[13]; const float* bk2 = (const float*)d_in[14];
  const float* Wv2 = (const float*)d_in[15]; const float* bv2 = (const float*)d_in[16];
  const float* Ws2 = (const float*)d_in[17]; const float* bs2 = (const float*)d_in[18];
  const float* Wl  = (const float*)d_in[19]; const float* bl  = (const float*)d_in[20];

  const int* srcIdx = ei;          // edge_index[0] (source j)
  const int* dstIdx = ei + NE;     // edge_index[1] (target i)

  // -------- workspace layout --------
  float* ws = (float*)d_ws;
  const size_t SZ_NODE = (size_t)NN * D1;       // 12.8M elems
  float* H2f  = ws;                              // NN*D1 fp32
  float* sums = ws + SZ_NODE;                    // NG*D1
  float* bc1  = sums + (size_t)NG * D1;          // 1024
  float* bc2  = bc1 + D4;                        // 1024
  short* Xb   = (short*)(bc2 + D4);              // NN*INC
  short* H1b  = Xb + (size_t)NN * INC;           // NN*D1
  short* QS   = H1b + SZ_NODE;                   // NN*512 bf16 (Q|S)
  short* Wtc1 = QS + (size_t)NN * 512;           // 1024*128
  short* Wtc2 = Wtc1 + (size_t)D4 * INC;         // 1024*256
  unsigned char* KV8 = (unsigned char*)(Wtc2 + (size_t)D4 * D1);  // NN*512 fp8
  int* ip      = (int*)(KV8 + (size_t)NN * 512);
  int* deg     = ip;                 // NN
  int* partial = deg + NN;           // 256
  int* rowstart= partial + 256;      // NN+1
  int* cursor  = rowstart + NN + 1;  // NN
  int* esrc    = cursor + NN;        // NE
  int* gb      = esrc + NE;          // NG+1

  const int mtiles = (NN + 127) / 128;           // 391
  const dim3 gemmGrid(64, (mtiles + 7) / 8);     // 64 x 49 swizzled
  const int edgeBlocks = (NE + 255) / 256;
  const int aggBlocks  = (NN + 3) / 4;
  const int cvtBlocks  = CVT_XB + CVT_W1B + CVT_W2B + CVT_BB + CVT_DB + CVT_SB;

  // ======== Converts + zeroing (one kernel) ========
  cvt_all_k<<<cvtBlocks, 256, 0, stream>>>(x, Xb,
      Wq1, Wk1, Wv1, Ws1, Wq2, Wk2, Wv2, Ws2, Wtc1, Wtc2,
      bq1, bk1, bv1, bs1, bq2, bk2, bv2, bs2, bc1, bc2, deg, sums);

  // ======== CSR build + graph bounds ========
  deg_count<<<edgeBlocks, 256, 0, stream>>>(dstIdx, deg);
  scan1<<<NB_SCAN + 1, 256, 0, stream>>>(deg, partial, batch, gb);
  scan3<<<NB_SCAN, 256, 0, stream>>>(deg, partial, rowstart, cursor);
  scatter_k<<<edgeBlocks, 256, 0, stream>>>(srcIdx, dstIdx, cursor, esrc);

  // ======== Layer 1 ========
  gemm_mfma<<<gemmGrid, 256, 0, stream>>>(Xb, Wtc1, bc1, QS, KV8, NN, INC);
  node_attn<short><<<aggBlocks, 256, 0, stream>>>(rowstart, esrc, QS, KV8, H1b);

  // ======== Layer 2 ========
  gemm_mfma<<<gemmGrid, 256, 0, stream>>>(H1b, Wtc2, bc2, QS, KV8, NN, D1);
  node_attn<float><<<aggBlocks, 256, 0, stream>>>(rowstart, esrc, QS, KV8, H2f);

  // ======== Pool + head ========
  pool_k<<<(NN + 63) / 64, 256, 0, stream>>>(H2f, batch, sums);
  head_k<<<1, 640, 0, stream>>>(sums, gb, Wl, bl, (float*)d_out);
}

// Round 5
// 347.458 us; speedup vs baseline: 1.1458x; 1.0293x over previous
//
#include <hip/hip_runtime.h>
#include <math.h>

constexpr int NN   = 50000;   // nodes
constexpr int NE   = 400000;  // edges
constexpr int INC  = 128;     // in channels
constexpr int NH   = 4;       // heads
constexpr int D1   = 256;     // NH*HIDC
constexpr int D4   = 1024;    // 4*D1 fused QKVS logical cols
constexpr int NOUT = 10;      // classes
constexpr int NG   = 64;      // graphs
constexpr int NB_SCAN = (NN + 255) / 256;   // 196 scan blocks

// GEMM output split per node:
//   QS[node][512] bf16 : cols 0..255 = Q, cols 256..511 = S
//   KV8[node][512] fp8 : byte j -> group g=j>>3, off=j&7: off<4 -> K ch 4g+off,
//                                                        off>=4 -> V ch 4g+(off-4)
// Lane t of node_attn reads 8 B at node*512 + t*8 = [K c0..c0+3 | V c0..c0+3].

typedef __attribute__((ext_vector_type(8))) short bf16x8;   // MFMA A/B frag
typedef __attribute__((ext_vector_type(4))) float f32x4;    // MFMA C/D frag
typedef __attribute__((ext_vector_type(2))) float f32x2;

// ---------- bf16 helpers ----------
__device__ __forceinline__ short f2b(float f) {
  union { float f; unsigned int i; } v; v.f = f;
  unsigned int x = v.i;
  return (short)((x + 0x7FFFu + ((x >> 16) & 1u)) >> 16);
}
__device__ __forceinline__ float b2f(short u) {
  union { unsigned int i; float f; } v; v.i = ((unsigned int)(unsigned short)u) << 16;
  return v.f;
}
__device__ __forceinline__ float4 ld4b(const short* p) {
  short4 u = *(const short4*)p;
  return make_float4(b2f(u.x), b2f(u.y), b2f(u.z), b2f(u.w));
}
// HW packed f32->bf16 (RNE, same rounding as f2b)
__device__ __forceinline__ int cvt_pk_bf16(float lo, float hi) {
  int r;
  asm volatile("v_cvt_pk_bf16_f32 %0, %1, %2" : "=v"(r) : "v"(lo), "v"(hi));
  return r;
}
// pack 4 floats -> 4 fp8 e4m3 bytes (HW convert)
__device__ __forceinline__ int pk_fp8x4(float a, float b, float c, float d) {
  int v = __builtin_amdgcn_cvt_pk_fp8_f32(a, b, 0, false);
  v = __builtin_amdgcn_cvt_pk_fp8_f32(c, d, v, true);
  return v;
}

// ---------- async global->LDS 16B ----------
__device__ __forceinline__ void gld_lds16(const short* g, short* l) {
  __builtin_amdgcn_global_load_lds(
      (const __attribute__((address_space(1))) unsigned int*)g,
      (__attribute__((address_space(3))) unsigned int*)l, 16, 0, 0);
}

// ---------- fused converts + zeroing (one dispatch) ----------
constexpr int CVT_XB  = (NN * INC / 4 + 255) / 256;   // 6250 blocks
constexpr int CVT_W1B = (4 * D1 * INC + 255) / 256;   // 512
constexpr int CVT_W2B = (4 * D1 * D1 + 255) / 256;    // 1024
constexpr int CVT_BB  = 8;                            // bias blocks
constexpr int CVT_DB  = (NN + 255) / 256;             // deg zero (196)
constexpr int CVT_SB  = (NG * D1 + 255) / 256;        // sums zero (64)

__device__ __forceinline__ void wt_one(const float* Wq, const float* Wk,
    const float* Wv, const float* Ws, short* Wt, int kbits, int i) {
  int K = 1 << kbits;
  int seg = i >> (kbits + 8);               // 0=Q 1=K 2=V 3=S
  int idx = i & ((D1 << kbits) - 1);
  int n = idx >> kbits, k = idx & (K - 1);
  const float* W = (seg == 0) ? Wq : (seg == 1) ? Wk : (seg == 2) ? Wv : Ws;
  int row;
  if (seg == 0)      row = n;
  else if (seg == 3) row = 768 + n;
  else               row = 256 + (n >> 2) * 8 + ((seg == 2) ? 4 : 0) + (n & 3);
  Wt[(size_t)row * K + k] = f2b(W[(size_t)k * D1 + n]);
}

__global__ void cvt_all_k(const float* __restrict__ x, short* __restrict__ Xb,
    const float* __restrict__ Wq1, const float* __restrict__ Wk1,
    const float* __restrict__ Wv1, const float* __restrict__ Ws1,
    const float* __restrict__ Wq2, const float* __restrict__ Wk2,
    const float* __restrict__ Wv2, const float* __restrict__ Ws2,
    short* __restrict__ Wtc1, short* __restrict__ Wtc2,
    const float* __restrict__ bq1, const float* __restrict__ bk1,
    const float* __restrict__ bv1, const float* __restrict__ bs1,
    const float* __restrict__ bq2, const float* __restrict__ bk2,
    const float* __restrict__ bv2, const float* __restrict__ bs2,
    float* __restrict__ bc1, float* __restrict__ bc2,
    int* __restrict__ deg, float* __restrict__ sums) {
  const int b = blockIdx.x;
  const int t = threadIdx.x;
  if (b < CVT_XB) {                               // x -> bf16 (4/thread)
    int i = (b * 256 + t) * 4;
    if (i >= NN * INC) return;
    float4 v = *(const float4*)(x + i);
    short4 o; o.x = f2b(v.x); o.y = f2b(v.y); o.z = f2b(v.z); o.w = f2b(v.w);
    *(short4*)(Xb + i) = o;
  } else if (b < CVT_XB + CVT_W1B) {              // layer-1 weights
    int i = (b - CVT_XB) * 256 + t;
    if (i < 4 * D1 * INC) wt_one(Wq1, Wk1, Wv1, Ws1, Wtc1, 7, i);
  } else if (b < CVT_XB + CVT_W1B + CVT_W2B) {    // layer-2 weights
    int i = (b - CVT_XB - CVT_W1B) * 256 + t;
    if (i < 4 * D1 * D1) wt_one(Wq2, Wk2, Wv2, Ws2, Wtc2, 8, i);
  } else if (b < CVT_XB + CVT_W1B + CVT_W2B + CVT_BB) {  // bias concat
    int i = (b - CVT_XB - CVT_W1B - CVT_W2B) * 256 + t;
    if (i >= 2 * D4) return;
    int row = i & (D4 - 1);
    const float* bq = (i < D4) ? bq1 : bq2;
    const float* bk = (i < D4) ? bk1 : bk2;
    const float* bv = (i < D4) ? bv1 : bv2;
    const float* bs = (i < D4) ? bs1 : bs2;
    float v;
    if (row < 256) v = bq[row];
    else if (row < 768) {
      int j = row - 256, grp = j >> 3, off = j & 7;
      int ch = grp * 4 + (off & 3);
      v = (off < 4) ? bk[ch] : bv[ch];
    } else v = bs[row - 768];
    ((i < D4) ? bc1 : bc2)[row] = v;
  } else if (b < CVT_XB + CVT_W1B + CVT_W2B + CVT_BB + CVT_DB) {  // deg = 0
    int i = (b - CVT_XB - CVT_W1B - CVT_W2B - CVT_BB) * 256 + t;
    if (i < NN) deg[i] = 0;
  } else {                                        // sums = 0
    int i = (b - CVT_XB - CVT_W1B - CVT_W2B - CVT_BB - CVT_DB) * 256 + t;
    if (i < NG * D1) sums[i] = 0.f;
  }
}

// ---------- CSR build ----------
__global__ void deg_count(const int* __restrict__ dst, int* __restrict__ deg) {
  int e = blockIdx.x * 256 + threadIdx.x;
  if (e < NE) atomicAdd(&deg[dst[e]], 1);
}
// block partial sums; extra block NB_SCAN does graph bounds (binary search)
__global__ __launch_bounds__(256) void scan1(const int* __restrict__ deg,
    int* __restrict__ partial, const int* __restrict__ batch, int* __restrict__ gb) {
  if (blockIdx.x == NB_SCAN) {
    int g = threadIdx.x;
    if (g > NG) return;
    int lo = 0, hi = NN;
    while (lo < hi) {
      int mid = (lo + hi) >> 1;
      if (batch[mid] < g) lo = mid + 1; else hi = mid;
    }
    gb[g] = lo;
    return;
  }
  __shared__ int sh[256];
  int t = threadIdx.x, i = blockIdx.x * 256 + t;
  sh[t] = (i < NN) ? deg[i] : 0;
  __syncthreads();
  for (int off = 128; off > 0; off >>= 1) {
    if (t < off) sh[t] += sh[t + off];
    __syncthreads();
  }
  if (t == 0) partial[blockIdx.x] = sh[0];
}
__global__ __launch_bounds__(256) void scan3(const int* __restrict__ deg,
    const int* __restrict__ partial, int* __restrict__ rowstart,
    int* __restrict__ cursor) {
  __shared__ int sh[256];
  __shared__ int base_s;
  const int t = threadIdx.x;
  int pv = (t < NB_SCAN) ? partial[t] : 0;
  sh[t] = pv;
  __syncthreads();
  for (int off = 1; off < 256; off <<= 1) {
    int o = (t >= off) ? sh[t - off] : 0;
    __syncthreads();
    sh[t] += o;
    __syncthreads();
  }
  if (t == 0) base_s = (blockIdx.x == 0) ? 0 : sh[blockIdx.x - 1];
  __syncthreads();
  const int base = base_s;
  __syncthreads();
  int i = blockIdx.x * 256 + t;
  int v = (i < NN) ? deg[i] : 0;
  sh[t] = v;
  __syncthreads();
  for (int off = 1; off < 256; off <<= 1) {
    int o = (t >= off) ? sh[t - off] : 0;
    __syncthreads();
    sh[t] += o;
    __syncthreads();
  }
  int excl = sh[t] - v + base;
  if (i <= NN) rowstart[i] = excl;
  if (i < NN)  cursor[i]   = excl;
}
__global__ void scatter_k(const int* __restrict__ src, const int* __restrict__ dst,
    int* __restrict__ cursor, int* __restrict__ esrc) {
  int e = blockIdx.x * 256 + threadIdx.x;
  if (e >= NE) return;
  int d = dst[e];
  int pos = atomicAdd(&cursor[d], 1);
  esrc[pos] = src[e];
}

// ---------- MFMA GEMM: [QS bf16 | KV8 fp8] = Xb[M,K] @ Wt[1024,K]^T + bias ----
// Swapped-operand MFMA (C^T fragments): lane holds 4 CONSECUTIVE output cols.
// XOR-swizzled LDS staging (conflict-free K-loop). Double-buffered K-step=32,
// ONE barrier per step. 2-pass 64-row epilogue (LDS 32768 B) + launch_bounds
// (256,4): total regs <=128 (64 arch + 64 AGPR acc) -> 4 blocks/CU.
constexpr int CLDS = 136;   // C-tile LDS stride in shorts

__global__ __launch_bounds__(256, 4) void gemm_mfma(
    const short* __restrict__ Xb, const short* __restrict__ Wt,
    const float* __restrict__ bias, short* __restrict__ QS,
    unsigned char* __restrict__ KV8, int M, int K) {
  __shared__ short smem[16384];   // 32768 B: A0|B0|A1|B1 staging; epilogue reuse
  const int bx = blockIdx.x;                 // 0..63
  const int by = blockIdx.y;
  const int m_tile = (bx & 7) + (by << 3);   // XCD swizzle
  const int n_tile = bx >> 3;                // 0..7
  const int m0 = m_tile * 128;
  if (m0 >= M) return;
  const int n0 = n_tile * 128;

  const int t    = threadIdx.x;
  const int lane = t & 63;
  const int wv   = t >> 6;
  const int wm   = (wv >> 1) * 64;
  const int wn   = (wv & 1) * 64;
  const int quad = lane >> 4;
  const int l16  = lane & 15;
  const int lrow = lane >> 2;
  const int lseg = lane & 3;

  const int swz_w = (lseg ^ ((lrow >> 1) & 3)) * 8;   // staging source swizzle
  const int swz_r = (quad ^ ((l16 >> 1) & 3)) * 8;    // fragment read swizzle

  f32x4 acc[4][4] = {};

  // prologue: stage tile k0=0 into buffer 0
  {
#pragma unroll
    for (int j = 0; j < 2; ++j) {
      const int rb = (wv * 2 + j) * 16;      // 16 rows per issue per matrix
      int gm = m0 + rb + lrow;
      gm = gm < M ? gm : M - 1;
      gld_lds16(Xb + (size_t)gm * K + swz_w,              &smem[rb * 32]);
      gld_lds16(Wt + (size_t)(n0 + rb + lrow) * K + swz_w, &smem[4096 + rb * 32]);
    }
  }
  __syncthreads();

  int cur = 0;
  for (int k0 = 0; k0 < K; k0 += 32) {
    // prefetch next K-tile into the other buffer (overlaps with compute)
    if (k0 + 32 < K) {
      short* An = &smem[(cur ^ 1) * 8192];
      short* Bn = &smem[(cur ^ 1) * 8192 + 4096];
#pragma unroll
      for (int j = 0; j < 2; ++j) {
        const int rb = (wv * 2 + j) * 16;
        int gm = m0 + rb + lrow;
        gm = gm < M ? gm : M - 1;
        gld_lds16(Xb + (size_t)gm * K + k0 + 32 + swz_w,              &An[rb * 32]);
        gld_lds16(Wt + (size_t)(n0 + rb + lrow) * K + k0 + 32 + swz_w, &Bn[rb * 32]);
      }
    }
    // compute current buffer
    {
      const short* Ac = &smem[cur * 8192];
      const short* Bc = &smem[cur * 8192 + 4096];
      bf16x8 a[4], b[4];
#pragma unroll
      for (int mi = 0; mi < 4; mi++)
        a[mi] = *(const bf16x8*)(&Ac[(wm + mi * 16 + l16) * 32 + swz_r]);
#pragma unroll
      for (int nj = 0; nj < 4; nj++)
        b[nj] = *(const bf16x8*)(&Bc[(wn + nj * 16 + l16) * 32 + swz_r]);
#pragma unroll
      for (int mi = 0; mi < 4; mi++)
#pragma unroll
        for (int nj = 0; nj < 4; nj++)
          acc[mi][nj] = __builtin_amdgcn_mfma_f32_16x16x32_bf16(b[nj], a[mi], acc[mi][nj], 0, 0, 0);
    }
    __syncthreads();   // waits prefetch (vmcnt) + guards buffer reuse
    cur ^= 1;
  }

  // ---- epilogue: 2 passes of 64 rows; bias+pack in-reg, LDS stage, copy-out -
  const bool isKV = (n_tile >= 2) && (n_tile <= 5);
  float4 bz[4];
#pragma unroll
  for (int nj = 0; nj < 4; nj++)
    bz[nj] = *(const float4*)(bias + n0 + wn + nj * 16 + quad * 4);
  const int kv_base = n0 - 256;
  const int qs_base = (n_tile < 2) ? n0 : (n0 - 512);   // Q cols or S cols

#pragma unroll
  for (int p = 0; p < 2; ++p) {
    if ((wv >> 1) == p) {                 // waves owning rows [p*64, p*64+64)
      if (isKV) {
        unsigned char* cs = (unsigned char*)smem;      // [64][136] bytes
#pragma unroll
        for (int mi = 0; mi < 4; mi++) {
          const int row = mi * 16 + l16;
#pragma unroll
          for (int nj = 0; nj < 4; nj++) {
            const int colb = wn + nj * 16 + quad * 4;
            const int pk = pk_fp8x4(acc[mi][nj][0] + bz[nj].x, acc[mi][nj][1] + bz[nj].y,
                                    acc[mi][nj][2] + bz[nj].z, acc[mi][nj][3] + bz[nj].w);
            *(int*)(cs + row * 136 + colb) = pk;
          }
        }
      } else {
#pragma unroll
        for (int mi = 0; mi < 4; mi++) {
          const int row = mi * 16 + l16;
#pragma unroll
          for (int nj = 0; nj < 4; nj++) {
            const int col = wn + nj * 16 + quad * 4;
            int2 o;
            o.x = cvt_pk_bf16(acc[mi][nj][0] + bz[nj].x, acc[mi][nj][1] + bz[nj].y);
            o.y = cvt_pk_bf16(acc[mi][nj][2] + bz[nj].z, acc[mi][nj][3] + bz[nj].w);
            *(int2*)(&smem[row * CLDS + col]) = o;
          }
        }
      }
    }
    __syncthreads();
    if (isKV) {
      const unsigned char* cs = (const unsigned char*)smem;
#pragma unroll
      for (int it = 0; it < 4; ++it) {
        const int chunk = it * 256 + t;       // 1024 chunks of 8 bytes
        const int row = chunk >> 4;
        const int cb  = (chunk & 15) * 8;
        const int gm  = m0 + p * 64 + row;
        if (gm < M)
          *(int2*)(KV8 + (size_t)gm * 512 + kv_base + cb) = *(const int2*)(cs + row * 136 + cb);
      }
    } else {
#pragma unroll
      for (int it = 0; it < 4; ++it) {
        const int chunk = it * 256 + t;       // 1024 chunks of 8 shorts
        const int row = chunk >> 4;
        const int cc  = (chunk & 15) * 8;
        const int gm  = m0 + p * 64 + row;
        if (gm < M)
          *(int4*)(QS + (size_t)gm * 512 + qs_base + cc) = *(const int4*)(&smem[row * CLDS + cc]);
      }
    }
    if (p == 0) __syncthreads();   // copy-out done before pass-1 overwrites LDS
  }
}

// ---------- fp8 KV decode (keep pairs packed for v_pk_* math) ----------
__device__ __forceinline__ f32x2 cvt_lo(int x) { return __builtin_amdgcn_cvt_pk_f32_fp8(x, false); }
__device__ __forceinline__ f32x2 cvt_hi(int x) { return __builtin_amdgcn_cvt_pk_f32_fp8(x, true); }

// ---------- DPP rotate-reduce over 16 lanes (pure VALU, no DS pipe) --------
template <int CTRL>
__device__ __forceinline__ float ror_add(float x) {
  int y = __builtin_amdgcn_update_dpp(0, __float_as_int(x), CTRL, 0xF, 0xF, true);
  return x + __int_as_float(y);
}
__device__ __forceinline__ float red16(float x) {
  x = ror_add<0x121>(x);   // row_ror:1
  x = ror_add<0x122>(x);   // row_ror:2
  x = ror_add<0x124>(x);   // row_ror:4
  x = ror_add<0x128>(x);   // row_ror:8
  return x;
}

// score scale: 1/sqrt(64) folded with log2(e) -> softmax runs in exp2 domain
#define SC2 (0.125f * 1.44269504088896341f)

// per-edge: decode K/V pairs, packed dot with Q, 16-lane reduce -> raw score
__device__ __forceinline__ float edge_score(const int2 x, f32x2 q01, f32x2 q23,
                                            f32x2& vv01, f32x2& vv23) {
  f32x2 kk01 = cvt_lo(x.x), kk23 = cvt_hi(x.x);
  vv01 = cvt_lo(x.y); vv23 = cvt_hi(x.y);
  f32x2 dd = q01 * kk01;
  dd += q23 * kk23;
  return red16(dd.x + dd.y);
}

// ---------- fused attention: online softmax (exp2 domain), fp8 KV ----------
template <typename TOUT>
__device__ __forceinline__ void st1(TOUT* p, float v);
template <> __device__ __forceinline__ void st1<float>(float* p, float v) { *p = v; }
template <> __device__ __forceinline__ void st1<short>(short* p, float v) { *p = f2b(v); }

template <typename TOUT>
__global__ __launch_bounds__(256) void node_attn(
    const int* __restrict__ rowstart, const int* __restrict__ esrc,
    const short* __restrict__ QS, const unsigned char* __restrict__ KV8,
    TOUT* __restrict__ out) {
  const int nid = blockIdx.x * 4 + (threadIdx.x >> 6);
  if (nid >= NN) return;
  const int t  = threadIdx.x & 63;
  const int c0 = t * 4;
  const int r0 = __builtin_amdgcn_readfirstlane(rowstart[nid]);
  const int r1 = __builtin_amdgcn_readfirstlane(rowstart[nid + 1]);
  const short4 qu = *(const short4*)(QS + (size_t)nid * 512 + c0);
  const f32x2 q01 = {b2f(qu.x), b2f(qu.y)};
  const f32x2 q23 = {b2f(qu.z), b2f(qu.w)};
  const unsigned char* kvb = KV8 + t * 8;
  float m = -INFINITY, denom = 0.f;
  f32x2 a01 = {0.f, 0.f}, a23 = {0.f, 0.f};
  int r = r0;
  for (; r + 7 < r1; r += 8) {
    const int e0 = __builtin_amdgcn_readfirstlane(esrc[r + 0]);
    const int e1 = __builtin_amdgcn_readfirstlane(esrc[r + 1]);
    const int e2 = __builtin_amdgcn_readfirstlane(esrc[r + 2]);
    const int e3 = __builtin_amdgcn_readfirstlane(esrc[r + 3]);
    const int e4 = __builtin_amdgcn_readfirstlane(esrc[r + 4]);
    const int e5 = __builtin_amdgcn_readfirstlane(esrc[r + 5]);
    const int e6 = __builtin_amdgcn_readfirstlane(esrc[r + 6]);
    const int e7 = __builtin_amdgcn_readfirstlane(esrc[r + 7]);
    const int2 x0 = *(const int2*)(kvb + (size_t)e0 * 512);
    const int2 x1 = *(const int2*)(kvb + (size_t)e1 * 512);
    const int2 x2 = *(const int2*)(kvb + (size_t)e2 * 512);
    const int2 x3 = *(const int2*)(kvb + (size_t)e3 * 512);
    const int2 x4 = *(const int2*)(kvb + (size_t)e4 * 512);
    const int2 x5 = *(const int2*)(kvb + (size_t)e5 * 512);
    const int2 x6 = *(const int2*)(kvb + (size_t)e6 * 512);
    const int2 x7 = *(const int2*)(kvb + (size_t)e7 * 512);
    f32x2 v01_0, v23_0, v01_1, v23_1, v01_2, v23_2, v01_3, v23_3;
    f32x2 v01_4, v23_4, v01_5, v23_5, v01_6, v23_6, v01_7, v23_7;
    const float s0 = edge_score(x0, q01, q23, v01_0, v23_0) * SC2;
    const float s1 = edge_score(x1, q01, q23, v01_1, v23_1) * SC2;
    const float s2 = edge_score(x2, q01, q23, v01_2, v23_2) * SC2;
    const float s3 = edge_score(x3, q01, q23, v01_3, v23_3) * SC2;
    const float s4 = edge_score(x4, q01, q23, v01_4, v23_4) * SC2;
    const float s5 = edge_score(x5, q01, q23, v01_5, v23_5) * SC2;
    const float s6 = edge_score(x6, q01, q23, v01_6, v23_6) * SC2;
    const float s7 = edge_score(x7, q01, q23, v01_7, v23_7) * SC2;
    const float t01 = fmaxf(s0, s1), t23 = fmaxf(s2, s3);
    const float t45 = fmaxf(s4, s5), t67 = fmaxf(s6, s7);
    const float nm = fmaxf(fmaxf(m, fmaxf(t01, t23)), fmaxf(t45, t67));
    const float sc  = exp2f(m - nm);
    const float ex0 = exp2f(s0 - nm);
    const float ex1 = exp2f(s1 - nm);
    const float ex2 = exp2f(s2 - nm);
    const float ex3 = exp2f(s3 - nm);
    const float ex4 = exp2f(s4 - nm);
    const float ex5 = exp2f(s5 - nm);
    const float ex6 = exp2f(s6 - nm);
    const float ex7 = exp2f(s7 - nm);
    denom = denom * sc + ((ex0 + ex1) + (ex2 + ex3)) + ((ex4 + ex5) + (ex6 + ex7));
    const f32x2 scv = {sc, sc};
    a01 = a01 * scv; a23 = a23 * scv;
    a01 += f32x2{ex0, ex0} * v01_0; a23 += f32x2{ex0, ex0} * v23_0;
    a01 += f32x2{ex1, ex1} * v01_1; a23 += f32x2{ex1, ex1} * v23_1;
    a01 += f32x2{ex2, ex2} * v01_2; a23 += f32x2{ex2, ex2} * v23_2;
    a01 += f32x2{ex3, ex3} * v01_3; a23 += f32x2{ex3, ex3} * v23_3;
    a01 += f32x2{ex4, ex4} * v01_4; a23 += f32x2{ex4, ex4} * v23_4;
    a01 += f32x2{ex5, ex5} * v01_5; a23 += f32x2{ex5, ex5} * v23_5;
    a01 += f32x2{ex6, ex6} * v01_6; a23 += f32x2{ex6, ex6} * v23_6;
    a01 += f32x2{ex7, ex7} * v01_7; a23 += f32x2{ex7, ex7} * v23_7;
    m = nm;
  }
  for (; r + 3 < r1; r += 4) {
    const int e0 = __builtin_amdgcn_readfirstlane(esrc[r + 0]);
    const int e1 = __builtin_amdgcn_readfirstlane(esrc[r + 1]);
    const int e2 = __builtin_amdgcn_readfirstlane(esrc[r + 2]);
    const int e3 = __builtin_amdgcn_readfirstlane(esrc[r + 3]);
    const int2 x0 = *(const int2*)(kvb + (size_t)e0 * 512);
    const int2 x1 = *(const int2*)(kvb + (size_t)e1 * 512);
    const int2 x2 = *(const int2*)(kvb + (size_t)e2 * 512);
    const int2 x3 = *(const int2*)(kvb + (size_t)e3 * 512);
    f32x2 v01_0, v23_0, v01_1, v23_1, v01_2, v23_2, v01_3, v23_3;
    const float s0 = edge_score(x0, q01, q23, v01_0, v23_0) * SC2;
    const float s1 = edge_score(x1, q01, q23, v01_1, v23_1) * SC2;
    const float s2 = edge_score(x2, q01, q23, v01_2, v23_2) * SC2;
    const float s3 = edge_score(x3, q01, q23, v01_3, v23_3) * SC2;
    const float nm = fmaxf(fmaxf(m, fmaxf(s0, s1)), fmaxf(s2, s3));
    const float sc  = exp2f(m - nm);
    const float ex0 = exp2f(s0 - nm);
    const float ex1 = exp2f(s1 - nm);
    const float ex2 = exp2f(s2 - nm);
    const float ex3 = exp2f(s3 - nm);
    denom = denom * sc + ex0 + ex1 + ex2 + ex3;
    const f32x2 scv = {sc, sc};
    a01 = a01 * scv; a23 = a23 * scv;
    a01 += f32x2{ex0, ex0} * v01_0; a23 += f32x2{ex0, ex0} * v23_0;
    a01 += f32x2{ex1, ex1} * v01_1; a23 += f32x2{ex1, ex1} * v23_1;
    a01 += f32x2{ex2, ex2} * v01_2; a23 += f32x2{ex2, ex2} * v23_2;
    a01 += f32x2{ex3, ex3} * v01_3; a23 += f32x2{ex3, ex3} * v23_3;
    m = nm;
  }
  for (; r < r1; r++) {
    const int e0 = __builtin_amdgcn_readfirstlane(esrc[r]);
    const int2 x0 = *(const int2*)(kvb + (size_t)e0 * 512);
    f32x2 v01_0, v23_0;
    const float s0 = edge_score(x0, q01, q23, v01_0, v23_0) * SC2;
    const float nm = fmaxf(m, s0);
    const float sc  = exp2f(m - nm);
    const float ex0 = exp2f(s0 - nm);
    denom = denom * sc + ex0;
    const f32x2 scv = {sc, sc};
    a01 = a01 * scv; a23 = a23 * scv;
    a01 += f32x2{ex0, ex0} * v01_0; a23 += f32x2{ex0, ex0} * v23_0;
    m = nm;
  }
  const float inv = 1.0f / (denom + 1e-16f);
  const float4 sk = ld4b(QS + (size_t)nid * 512 + 256 + c0);
  float o0 = a01.x * inv + sk.x;
  float o1 = a01.y * inv + sk.y;
  float o2 = a23.x * inv + sk.z;
  float o3 = a23.y * inv + sk.w;
  o0 = o0 > 0.f ? o0 : expm1f(o0);
  o1 = o1 > 0.f ? o1 : expm1f(o1);
  o2 = o2 > 0.f ? o2 : expm1f(o2);
  o3 = o3 > 0.f ? o3 : expm1f(o3);
  TOUT* p = out + (size_t)nid * D1 + c0;
  st1<TOUT>(p + 0, o0); st1<TOUT>(p + 1, o1);
  st1<TOUT>(p + 2, o2); st1<TOUT>(p + 3, o3);
}

// ---------- mean-pool partial sums (parallel, run-length atomics) ----------
__global__ __launch_bounds__(256) void pool_k(const float* __restrict__ h,
    const int* __restrict__ batch, float* __restrict__ sums) {
  const int c = threadIdx.x;
  const int n0 = blockIdx.x * 64;
  const int n1 = min(n0 + 64, NN);
  float run = 0.f;
  int curg = -1;
  for (int n = n0; n < n1; n++) {
    int g = batch[n];
    if (g != curg) {
      if (curg >= 0) atomicAdd(&sums[(size_t)curg * D1 + c], run);
      run = 0.f; curg = g;
    }
    run += h[(size_t)n * D1 + c];
  }
  if (curg >= 0) atomicAdd(&sums[(size_t)curg * D1 + c], run);
}

// ---------- classifier + log_softmax (counts from gb) ----------
__global__ __launch_bounds__(640) void head_k(const float* __restrict__ sums,
    const int* __restrict__ gb, const float* __restrict__ Wl,
    const float* __restrict__ bl, float* __restrict__ out) {
  __shared__ float logits[NG][NOUT];
  const int t = threadIdx.x;
  if (t < NG * NOUT) {
    int g = t / NOUT, o = t % NOUT;
    float inv = 1.0f / fmaxf((float)(gb[g + 1] - gb[g]), 1.0f);
    float acc = 0.f;
    for (int k = 0; k < D1; k++) acc += sums[(size_t)g * D1 + k] * Wl[k * NOUT + o];
    logits[g][o] = acc * inv + bl[o];
  }
  __syncthreads();
  if (t < NG) {
    float mx = -INFINITY;
#pragma unroll
    for (int o = 0; o < NOUT; o++) mx = fmaxf(mx, logits[t][o]);
    float s = 0.f;
#pragma unroll
    for (int o = 0; o < NOUT; o++) s += __expf(logits[t][o] - mx);
    float lse = mx + logf(s);
#pragma unroll
    for (int o = 0; o < NOUT; o++) out[t * NOUT + o] = logits[t][o] - lse;
  }
}

// ---------------------------------------------------------------------------
extern "C" void kernel_launch(void* const* d_in, const int* in_sizes, int n_in,
                              void* d_out, int out_size, void* d_ws, size_t ws_size,
                              hipStream_t stream) {
  const float* x   = (const float*)d_in[0];
  const int* ei    = (const int*)d_in[1];
  const int* batch = (const int*)d_in[2];
  const float* Wq1 = (const float*)d_in[3];  const float* bq1 = (const float*)d_in[4];
  const float* Wk1 = (const float*)d_in[5];  const float* bk1 = (const float*)d_in[6];
  const float* Wv1 = (const float*)d_in[7];  const float* bv1 = (const float*)d_in[8];
  const float* Ws1 = (const float*)d_in[9];  const float* bs1 = (const float*)d_in[10];
  const float* Wq2 = (const float*)d_in[11]; const float* bq2 = (const float*)d_in[12];
  const float* Wk2 = (const float*)d_in[13]; const float* bk2 = (const float*)d_in[14];
  const float* Wv2 = (const float*)d_in[15]; const float* bv2 = (const float*)d_in[16];
  const float* Ws2 = (const float*)d_in[17]; const float* bs2 = (const float*)d_in[18];
  const float* Wl  = (const float*)d_in[19]; const float* bl  = (const float*)d_in[20];

  const int* srcIdx = ei;          // edge_index[0] (source j)
  const int* dstIdx = ei + NE;     // edge_index[1] (target i)

  // -------- workspace layout --------
  float* ws = (float*)d_ws;
  const size_t SZ_NODE = (size_t)NN * D1;       // 12.8M elems
  float* H2f  = ws;                              // NN*D1 fp32
  float* sums = ws + SZ_NODE;                    // NG*D1
  float* bc1  = sums + (size_t)NG * D1;          // 1024
  float* bc2  = bc1 + D4;                        // 1024
  short* Xb   = (short*)(bc2 + D4);              // NN*INC
  short* H1b  = Xb + (size_t)NN * INC;           // NN*D1
  short* QS   = H1b + SZ_NODE;                   // NN*512 bf16 (Q|S)
  short* Wtc1 = QS + (size_t)NN * 512;           // 1024*128
  short* Wtc2 = Wtc1 + (size_t)D4 * INC;         // 1024*256
  unsigned char* KV8 = (unsigned char*)(Wtc2 + (size_t)D4 * D1);  // NN*512 fp8
  int* ip      = (int*)(KV8 + (size_t)NN * 512);
  int* deg     = ip;                 // NN
  int* partial = deg + NN;           // 256
  int* rowstart= partial + 256;      // NN+1
  int* cursor  = rowstart + NN + 1;  // NN
  int* esrc    = cursor + NN;        // NE
  int* gb      = esrc + NE;          // NG+1

  const int mtiles = (NN + 127) / 128;           // 391
  const dim3 gemmGrid(64, (mtiles + 7) / 8);     // 64 x 49 swizzled
  const int edgeBlocks = (NE + 255) / 256;
  const int aggBlocks  = (NN + 3) / 4;
  const int cvtBlocks  = CVT_XB + CVT_W1B + CVT_W2B + CVT_BB + CVT_DB + CVT_SB;

  // ======== Converts + zeroing (one kernel) ========
  cvt_all_k<<<cvtBlocks, 256, 0, stream>>>(x, Xb,
      Wq1, Wk1, Wv1, Ws1, Wq2, Wk2, Wv2, Ws2, Wtc1, Wtc2,
      bq1, bk1, bv1, bs1, bq2, bk2, bv2, bs2, bc1, bc2, deg, sums);

  // ======== CSR build + graph bounds ========
  deg_count<<<edgeBlocks, 256, 0, stream>>>(dstIdx, deg);
  scan1<<<NB_SCAN + 1, 256, 0, stream>>>(deg, partial, batch, gb);
  scan3<<<NB_SCAN, 256, 0, stream>>>(deg, partial, rowstart, cursor);
  scatter_k<<<edgeBlocks, 256, 0, stream>>>(srcIdx, dstIdx, cursor, esrc);

  // ======== Layer 1 ========
  gemm_mfma<<<gemmGrid, 256, 0, stream>>>(Xb, Wtc1, bc1, QS, KV8, NN, INC);
  node_attn<short><<<aggBlocks, 256, 0, stream>>>(rowstart, esrc, QS, KV8, H1b);

  // ======== Layer 2 ========
  gemm_mfma<<<gemmGrid, 256, 0, stream>>>(H1b, Wtc2, bc2, QS, KV8, NN, D1);
  node_attn<float><<<aggBlocks, 256, 0, stream>>>(rowstart, esrc, QS, KV8, H2f);

  // ======== Pool + head ========
  pool_k<<<(NN + 63) / 64, 256, 0, stream>>>(H2f, batch, sums);
  head_k<<<1, 640, 0, stream>>>(sums, gb, Wl, bl, (float*)d_out);
}

// Round 6
// 341.545 us; speedup vs baseline: 1.1656x; 1.0173x over previous
//
#include <hip/hip_runtime.h>
#include <math.h>

constexpr int NN   = 50000;   // nodes
constexpr int NE   = 400000;  // edges
constexpr int INC  = 128;     // in channels
constexpr int NH   = 4;       // heads
constexpr int D1   = 256;     // NH*HIDC
constexpr int D4   = 1024;    // 4*D1 fused QKVS logical cols
constexpr int NOUT = 10;      // classes
constexpr int NG   = 64;      // graphs
constexpr int NB_SCAN = (NN + 255) / 256;   // 196 scan blocks

// GEMM output split per node:
//   QS[node][512] bf16 : cols 0..255 = Q, cols 256..511 = S
//   KV8[node][512] fp8 : byte j -> group g=j>>3, off=j&7: off<4 -> K ch 4g+off,
//                                                        off>=4 -> V ch 4g+(off-4)
// Lane t of node_attn reads 8 B at node*512 + t*8 = [K c0..c0+3 | V c0..c0+3].

typedef __attribute__((ext_vector_type(8))) short bf16x8;   // MFMA A/B frag
typedef __attribute__((ext_vector_type(4))) float f32x4;    // MFMA C/D frag
typedef __attribute__((ext_vector_type(2))) float f32x2;

// ---------- bf16 helpers ----------
__device__ __forceinline__ short f2b(float f) {
  union { float f; unsigned int i; } v; v.f = f;
  unsigned int x = v.i;
  return (short)((x + 0x7FFFu + ((x >> 16) & 1u)) >> 16);
}
__device__ __forceinline__ float b2f(short u) {
  union { unsigned int i; float f; } v; v.i = ((unsigned int)(unsigned short)u) << 16;
  return v.f;
}
__device__ __forceinline__ float4 ld4b(const short* p) {
  short4 u = *(const short4*)p;
  return make_float4(b2f(u.x), b2f(u.y), b2f(u.z), b2f(u.w));
}
// HW packed f32->bf16 (RNE, same rounding as f2b)
__device__ __forceinline__ int cvt_pk_bf16(float lo, float hi) {
  int r;
  asm volatile("v_cvt_pk_bf16_f32 %0, %1, %2" : "=v"(r) : "v"(lo), "v"(hi));
  return r;
}
// pack 4 floats -> 4 fp8 e4m3 bytes (HW convert)
__device__ __forceinline__ int pk_fp8x4(float a, float b, float c, float d) {
  int v = __builtin_amdgcn_cvt_pk_fp8_f32(a, b, 0, false);
  v = __builtin_amdgcn_cvt_pk_fp8_f32(c, d, v, true);
  return v;
}

// ---------- async global->LDS 16B ----------
__device__ __forceinline__ void gld_lds16(const short* g, short* l) {
  __builtin_amdgcn_global_load_lds(
      (const __attribute__((address_space(1))) unsigned int*)g,
      (__attribute__((address_space(3))) unsigned int*)l, 16, 0, 0);
}

// ---------- fused converts + zeroing (one dispatch) ----------
constexpr int CVT_XB  = (NN * INC / 4 + 255) / 256;   // 6250 blocks
constexpr int CVT_W1B = (4 * D1 * INC + 255) / 256;   // 512
constexpr int CVT_W2B = (4 * D1 * D1 + 255) / 256;    // 1024
constexpr int CVT_BB  = 8;                            // bias blocks
constexpr int CVT_DB  = (NN + 255) / 256;             // deg zero (196)
constexpr int CVT_SB  = (NG * D1 + 255) / 256;        // sums zero (64)

// coalesced-read decomposition: n inner (consecutive threads -> consecutive
// W addresses), k outer; the scattered side is the WRITE (fire-and-forget).
__device__ __forceinline__ void wt_one(const float* Wq, const float* Wk,
    const float* Wv, const float* Ws, short* Wt, int kbits, int i) {
  int K = 1 << kbits;
  int seg = i >> (kbits + 8);               // 0=Q 1=K 2=V 3=S
  int rem = i & ((D1 << kbits) - 1);
  int n = rem & (D1 - 1), k = rem >> 8;
  const float* W = (seg == 0) ? Wq : (seg == 1) ? Wk : (seg == 2) ? Wv : Ws;
  int row;
  if (seg == 0)      row = n;
  else if (seg == 3) row = 768 + n;
  else               row = 256 + (n >> 2) * 8 + ((seg == 2) ? 4 : 0) + (n & 3);
  Wt[(size_t)row * K + k] = f2b(W[(size_t)k * D1 + n]);
}

__global__ void cvt_all_k(const float* __restrict__ x, short* __restrict__ Xb,
    const float* __restrict__ Wq1, const float* __restrict__ Wk1,
    const float* __restrict__ Wv1, const float* __restrict__ Ws1,
    const float* __restrict__ Wq2, const float* __restrict__ Wk2,
    const float* __restrict__ Wv2, const float* __restrict__ Ws2,
    short* __restrict__ Wtc1, short* __restrict__ Wtc2,
    const float* __restrict__ bq1, const float* __restrict__ bk1,
    const float* __restrict__ bv1, const float* __restrict__ bs1,
    const float* __restrict__ bq2, const float* __restrict__ bk2,
    const float* __restrict__ bv2, const float* __restrict__ bs2,
    float* __restrict__ bc1, float* __restrict__ bc2,
    int* __restrict__ deg, float* __restrict__ sums) {
  const int b = blockIdx.x;
  const int t = threadIdx.x;
  if (b < CVT_XB) {                               // x -> bf16 (4/thread)
    int i = (b * 256 + t) * 4;
    if (i >= NN * INC) return;
    float4 v = *(const float4*)(x + i);
    short4 o; o.x = f2b(v.x); o.y = f2b(v.y); o.z = f2b(v.z); o.w = f2b(v.w);
    *(short4*)(Xb + i) = o;
  } else if (b < CVT_XB + CVT_W1B) {              // layer-1 weights
    int i = (b - CVT_XB) * 256 + t;
    if (i < 4 * D1 * INC) wt_one(Wq1, Wk1, Wv1, Ws1, Wtc1, 7, i);
  } else if (b < CVT_XB + CVT_W1B + CVT_W2B) {    // layer-2 weights
    int i = (b - CVT_XB - CVT_W1B) * 256 + t;
    if (i < 4 * D1 * D1) wt_one(Wq2, Wk2, Wv2, Ws2, Wtc2, 8, i);
  } else if (b < CVT_XB + CVT_W1B + CVT_W2B + CVT_BB) {  // bias concat
    int i = (b - CVT_XB - CVT_W1B - CVT_W2B) * 256 + t;
    if (i >= 2 * D4) return;
    int row = i & (D4 - 1);
    const float* bq = (i < D4) ? bq1 : bq2;
    const float* bk = (i < D4) ? bk1 : bk2;
    const float* bv = (i < D4) ? bv1 : bv2;
    const float* bs = (i < D4) ? bs1 : bs2;
    float v;
    if (row < 256) v = bq[row];
    else if (row < 768) {
      int j = row - 256, grp = j >> 3, off = j & 7;
      int ch = grp * 4 + (off & 3);
      v = (off < 4) ? bk[ch] : bv[ch];
    } else v = bs[row - 768];
    ((i < D4) ? bc1 : bc2)[row] = v;
  } else if (b < CVT_XB + CVT_W1B + CVT_W2B + CVT_BB + CVT_DB) {  // deg = 0
    int i = (b - CVT_XB - CVT_W1B - CVT_W2B - CVT_BB) * 256 + t;
    if (i < NN) deg[i] = 0;
  } else {                                        // sums = 0
    int i = (b - CVT_XB - CVT_W1B - CVT_W2B - CVT_BB - CVT_DB) * 256 + t;
    if (i < NG * D1) sums[i] = 0.f;
  }
}

// ---------- CSR build ----------
__global__ void deg_count(const int* __restrict__ dst, int* __restrict__ deg) {
  int e = blockIdx.x * 256 + threadIdx.x;
  if (e < NE) atomicAdd(&deg[dst[e]], 1);
}
// block partial sums; extra block NB_SCAN does graph bounds (binary search)
__global__ __launch_bounds__(256) void scan1(const int* __restrict__ deg,
    int* __restrict__ partial, const int* __restrict__ batch, int* __restrict__ gb) {
  if (blockIdx.x == NB_SCAN) {
    int g = threadIdx.x;
    if (g > NG) return;
    int lo = 0, hi = NN;
    while (lo < hi) {
      int mid = (lo + hi) >> 1;
      if (batch[mid] < g) lo = mid + 1; else hi = mid;
    }
    gb[g] = lo;
    return;
  }
  __shared__ int sh[256];
  int t = threadIdx.x, i = blockIdx.x * 256 + t;
  sh[t] = (i < NN) ? deg[i] : 0;
  __syncthreads();
  for (int off = 128; off > 0; off >>= 1) {
    if (t < off) sh[t] += sh[t + off];
    __syncthreads();
  }
  if (t == 0) partial[blockIdx.x] = sh[0];
}
__global__ __launch_bounds__(256) void scan3(const int* __restrict__ deg,
    const int* __restrict__ partial, int* __restrict__ rowstart,
    int* __restrict__ cursor) {
  __shared__ int sh[256];
  __shared__ int base_s;
  const int t = threadIdx.x;
  int pv = (t < NB_SCAN) ? partial[t] : 0;
  sh[t] = pv;
  __syncthreads();
  for (int off = 1; off < 256; off <<= 1) {
    int o = (t >= off) ? sh[t - off] : 0;
    __syncthreads();
    sh[t] += o;
    __syncthreads();
  }
  if (t == 0) base_s = (blockIdx.x == 0) ? 0 : sh[blockIdx.x - 1];
  __syncthreads();
  const int base = base_s;
  __syncthreads();
  int i = blockIdx.x * 256 + t;
  int v = (i < NN) ? deg[i] : 0;
  sh[t] = v;
  __syncthreads();
  for (int off = 1; off < 256; off <<= 1) {
    int o = (t >= off) ? sh[t - off] : 0;
    __syncthreads();
    sh[t] += o;
    __syncthreads();
  }
  int excl = sh[t] - v + base;
  if (i <= NN) rowstart[i] = excl;
  if (i < NN)  cursor[i]   = excl;
}
__global__ void scatter_k(const int* __restrict__ src, const int* __restrict__ dst,
    int* __restrict__ cursor, int* __restrict__ esrc) {
  int e = blockIdx.x * 256 + threadIdx.x;
  if (e >= NE) return;
  int d = dst[e];
  int pos = atomicAdd(&cursor[d], 1);
  esrc[pos] = src[e];
}

// ---------- MFMA GEMM: [QS bf16 | KV8 fp8] = Xb[M,K] @ Wt[1024,K]^T + bias ----
// Swapped-operand MFMA (C^T fragments): lane holds 4 CONSECUTIVE output cols.
// XOR-swizzled LDS staging (conflict-free K-loop). Double-buffered K-step=32,
// ONE barrier per step. 2-pass 64-row epilogue (LDS 32768 B) + launch_bounds
// (256,4): total regs <=128 (64 arch + 64 AGPR acc) -> 4 blocks/CU.
constexpr int CLDS = 136;   // C-tile LDS stride in shorts

__global__ __launch_bounds__(256, 4) void gemm_mfma(
    const short* __restrict__ Xb, const short* __restrict__ Wt,
    const float* __restrict__ bias, short* __restrict__ QS,
    unsigned char* __restrict__ KV8, int M, int K) {
  __shared__ short smem[16384];   // 32768 B: A0|B0|A1|B1 staging; epilogue reuse
  const int bx = blockIdx.x;                 // 0..63
  const int by = blockIdx.y;
  const int m_tile = (bx & 7) + (by << 3);   // XCD swizzle
  const int n_tile = bx >> 3;                // 0..7
  const int m0 = m_tile * 128;
  if (m0 >= M) return;
  const int n0 = n_tile * 128;

  const int t    = threadIdx.x;
  const int lane = t & 63;
  const int wv   = t >> 6;
  const int wm   = (wv >> 1) * 64;
  const int wn   = (wv & 1) * 64;
  const int quad = lane >> 4;
  const int l16  = lane & 15;
  const int lrow = lane >> 2;
  const int lseg = lane & 3;

  const int swz_w = (lseg ^ ((lrow >> 1) & 3)) * 8;   // staging source swizzle
  const int swz_r = (quad ^ ((l16 >> 1) & 3)) * 8;    // fragment read swizzle

  f32x4 acc[4][4] = {};

  // prologue: stage tile k0=0 into buffer 0
  {
#pragma unroll
    for (int j = 0; j < 2; ++j) {
      const int rb = (wv * 2 + j) * 16;      // 16 rows per issue per matrix
      int gm = m0 + rb + lrow;
      gm = gm < M ? gm : M - 1;
      gld_lds16(Xb + (size_t)gm * K + swz_w,              &smem[rb * 32]);
      gld_lds16(Wt + (size_t)(n0 + rb + lrow) * K + swz_w, &smem[4096 + rb * 32]);
    }
  }
  __syncthreads();

  int cur = 0;
  for (int k0 = 0; k0 < K; k0 += 32) {
    // prefetch next K-tile into the other buffer (overlaps with compute)
    if (k0 + 32 < K) {
      short* An = &smem[(cur ^ 1) * 8192];
      short* Bn = &smem[(cur ^ 1) * 8192 + 4096];
#pragma unroll
      for (int j = 0; j < 2; ++j) {
        const int rb = (wv * 2 + j) * 16;
        int gm = m0 + rb + lrow;
        gm = gm < M ? gm : M - 1;
        gld_lds16(Xb + (size_t)gm * K + k0 + 32 + swz_w,              &An[rb * 32]);
        gld_lds16(Wt + (size_t)(n0 + rb + lrow) * K + k0 + 32 + swz_w, &Bn[rb * 32]);
      }
    }
    // compute current buffer
    {
      const short* Ac = &smem[cur * 8192];
      const short* Bc = &smem[cur * 8192 + 4096];
      bf16x8 a[4], b[4];
#pragma unroll
      for (int mi = 0; mi < 4; mi++)
        a[mi] = *(const bf16x8*)(&Ac[(wm + mi * 16 + l16) * 32 + swz_r]);
#pragma unroll
      for (int nj = 0; nj < 4; nj++)
        b[nj] = *(const bf16x8*)(&Bc[(wn + nj * 16 + l16) * 32 + swz_r]);
#pragma unroll
      for (int mi = 0; mi < 4; mi++)
#pragma unroll
        for (int nj = 0; nj < 4; nj++)
          acc[mi][nj] = __builtin_amdgcn_mfma_f32_16x16x32_bf16(b[nj], a[mi], acc[mi][nj], 0, 0, 0);
    }
    __syncthreads();   // waits prefetch (vmcnt) + guards buffer reuse
    cur ^= 1;
  }

  // ---- epilogue: 2 passes of 64 rows; bias+pack in-reg, LDS stage, copy-out -
  const bool isKV = (n_tile >= 2) && (n_tile <= 5);
  float4 bz[4];
#pragma unroll
  for (int nj = 0; nj < 4; nj++)
    bz[nj] = *(const float4*)(bias + n0 + wn + nj * 16 + quad * 4);
  const int kv_base = n0 - 256;
  const int qs_base = (n_tile < 2) ? n0 : (n0 - 512);   // Q cols or S cols

#pragma unroll
  for (int p = 0; p < 2; ++p) {
    if ((wv >> 1) == p) {                 // waves owning rows [p*64, p*64+64)
      if (isKV) {
        unsigned char* cs = (unsigned char*)smem;      // [64][136] bytes
#pragma unroll
        for (int mi = 0; mi < 4; mi++) {
          const int row = mi * 16 + l16;
#pragma unroll
          for (int nj = 0; nj < 4; nj++) {
            const int colb = wn + nj * 16 + quad * 4;
            const int pk = pk_fp8x4(acc[mi][nj][0] + bz[nj].x, acc[mi][nj][1] + bz[nj].y,
                                    acc[mi][nj][2] + bz[nj].z, acc[mi][nj][3] + bz[nj].w);
            *(int*)(cs + row * 136 + colb) = pk;
          }
        }
      } else {
#pragma unroll
        for (int mi = 0; mi < 4; mi++) {
          const int row = mi * 16 + l16;
#pragma unroll
          for (int nj = 0; nj < 4; nj++) {
            const int col = wn + nj * 16 + quad * 4;
            int2 o;
            o.x = cvt_pk_bf16(acc[mi][nj][0] + bz[nj].x, acc[mi][nj][1] + bz[nj].y);
            o.y = cvt_pk_bf16(acc[mi][nj][2] + bz[nj].z, acc[mi][nj][3] + bz[nj].w);
            *(int2*)(&smem[row * CLDS + col]) = o;
          }
        }
      }
    }
    __syncthreads();
    if (isKV) {
      const unsigned char* cs = (const unsigned char*)smem;
#pragma unroll
      for (int it = 0; it < 4; ++it) {
        const int chunk = it * 256 + t;       // 1024 chunks of 8 bytes
        const int row = chunk >> 4;
        const int cb  = (chunk & 15) * 8;
        const int gm  = m0 + p * 64 + row;
        if (gm < M)
          *(int2*)(KV8 + (size_t)gm * 512 + kv_base + cb) = *(const int2*)(cs + row * 136 + cb);
      }
    } else {
#pragma unroll
      for (int it = 0; it < 4; ++it) {
        const int chunk = it * 256 + t;       // 1024 chunks of 8 shorts
        const int row = chunk >> 4;
        const int cc  = (chunk & 15) * 8;
        const int gm  = m0 + p * 64 + row;
        if (gm < M)
          *(int4*)(QS + (size_t)gm * 512 + qs_base + cc) = *(const int4*)(&smem[row * CLDS + cc]);
      }
    }
    if (p == 0) __syncthreads();   // copy-out done before pass-1 overwrites LDS
  }
}

// ---------- fp8 KV decode (keep pairs packed for v_pk_* math) ----------
__device__ __forceinline__ f32x2 cvt_lo(int x) { return __builtin_amdgcn_cvt_pk_f32_fp8(x, false); }
__device__ __forceinline__ f32x2 cvt_hi(int x) { return __builtin_amdgcn_cvt_pk_f32_fp8(x, true); }

// ---------- DPP rotate-reduce over 16 lanes (pure VALU, no DS pipe) --------
template <int CTRL>
__device__ __forceinline__ float ror_add(float x) {
  int y = __builtin_amdgcn_update_dpp(0, __float_as_int(x), CTRL, 0xF, 0xF, true);
  return x + __int_as_float(y);
}
__device__ __forceinline__ float red16(float x) {
  x = ror_add<0x121>(x);   // row_ror:1
  x = ror_add<0x122>(x);   // row_ror:2
  x = ror_add<0x124>(x);   // row_ror:4
  x = ror_add<0x128>(x);   // row_ror:8
  return x;
}

// score scale: 1/sqrt(64) folded with log2(e); pre-applied to q at load time
#define SC2 (0.125f * 1.44269504088896341f)

// per-edge: decode K/V pairs, packed dot with (pre-scaled) Q, 16-lane reduce
__device__ __forceinline__ float edge_score(const int2 x, f32x2 q01, f32x2 q23,
                                            f32x2& vv01, f32x2& vv23) {
  f32x2 kk01 = cvt_lo(x.x), kk23 = cvt_hi(x.x);
  vv01 = cvt_lo(x.y); vv23 = cvt_hi(x.y);
  f32x2 dd = q01 * kk01;
  dd += q23 * kk23;
  return red16(dd.x + dd.y);
}

// ---------- fused attention: online softmax (exp2 domain), fp8 KV ----------
template <typename TOUT>
__device__ __forceinline__ void st1(TOUT* p, float v);
template <> __device__ __forceinline__ void st1<float>(float* p, float v) { *p = v; }
template <> __device__ __forceinline__ void st1<short>(short* p, float v) { *p = f2b(v); }

template <typename TOUT>
__global__ __launch_bounds__(256) void node_attn(
    const int* __restrict__ rowstart, const int* __restrict__ esrc,
    const short* __restrict__ QS, const unsigned char* __restrict__ KV8,
    TOUT* __restrict__ out) {
  const int nid = blockIdx.x * 4 + (threadIdx.x >> 6);
  if (nid >= NN) return;
  const int t  = threadIdx.x & 63;
  const int c0 = t * 4;
  const int r0 = __builtin_amdgcn_readfirstlane(rowstart[nid]);
  const int r1 = __builtin_amdgcn_readfirstlane(rowstart[nid + 1]);
  const short4 qu = *(const short4*)(QS + (size_t)nid * 512 + c0);
  const f32x2 q01 = {b2f(qu.x) * SC2, b2f(qu.y) * SC2};
  const f32x2 q23 = {b2f(qu.z) * SC2, b2f(qu.w) * SC2};
  const unsigned char* kvb = KV8 + t * 8;
  float m = -INFINITY, denom = 0.f;
  f32x2 a01 = {0.f, 0.f}, a23 = {0.f, 0.f};
  int r = r0;
  for (; r + 7 < r1; r += 8) {
    const int e0 = __builtin_amdgcn_readfirstlane(esrc[r + 0]);
    const int e1 = __builtin_amdgcn_readfirstlane(esrc[r + 1]);
    const int e2 = __builtin_amdgcn_readfirstlane(esrc[r + 2]);
    const int e3 = __builtin_amdgcn_readfirstlane(esrc[r + 3]);
    const int e4 = __builtin_amdgcn_readfirstlane(esrc[r + 4]);
    const int e5 = __builtin_amdgcn_readfirstlane(esrc[r + 5]);
    const int e6 = __builtin_amdgcn_readfirstlane(esrc[r + 6]);
    const int e7 = __builtin_amdgcn_readfirstlane(esrc[r + 7]);
    const int2 x0 = *(const int2*)(kvb + (size_t)e0 * 512);
    const int2 x1 = *(const int2*)(kvb + (size_t)e1 * 512);
    const int2 x2 = *(const int2*)(kvb + (size_t)e2 * 512);
    const int2 x3 = *(const int2*)(kvb + (size_t)e3 * 512);
    const int2 x4 = *(const int2*)(kvb + (size_t)e4 * 512);
    const int2 x5 = *(const int2*)(kvb + (size_t)e5 * 512);
    const int2 x6 = *(const int2*)(kvb + (size_t)e6 * 512);
    const int2 x7 = *(const int2*)(kvb + (size_t)e7 * 512);
    f32x2 v01_0, v23_0, v01_1, v23_1, v01_2, v23_2, v01_3, v23_3;
    f32x2 v01_4, v23_4, v01_5, v23_5, v01_6, v23_6, v01_7, v23_7;
    const float s0 = edge_score(x0, q01, q23, v01_0, v23_0);
    const float s1 = edge_score(x1, q01, q23, v01_1, v23_1);
    const float s2 = edge_score(x2, q01, q23, v01_2, v23_2);
    const float s3 = edge_score(x3, q01, q23, v01_3, v23_3);
    const float s4 = edge_score(x4, q01, q23, v01_4, v23_4);
    const float s5 = edge_score(x5, q01, q23, v01_5, v23_5);
    const float s6 = edge_score(x6, q01, q23, v01_6, v23_6);
    const float s7 = edge_score(x7, q01, q23, v01_7, v23_7);
    const float t01 = fmaxf(s0, s1), t23 = fmaxf(s2, s3);
    const float t45 = fmaxf(s4, s5), t67 = fmaxf(s6, s7);
    const float nm = fmaxf(fmaxf(m, fmaxf(t01, t23)), fmaxf(t45, t67));
    const float sc  = exp2f(m - nm);
    const float ex0 = exp2f(s0 - nm);
    const float ex1 = exp2f(s1 - nm);
    const float ex2 = exp2f(s2 - nm);
    const float ex3 = exp2f(s3 - nm);
    const float ex4 = exp2f(s4 - nm);
    const float ex5 = exp2f(s5 - nm);
    const float ex6 = exp2f(s6 - nm);
    const float ex7 = exp2f(s7 - nm);
    denom = denom * sc + ((ex0 + ex1) + (ex2 + ex3)) + ((ex4 + ex5) + (ex6 + ex7));
    const f32x2 scv = {sc, sc};
    a01 = a01 * scv; a23 = a23 * scv;
    a01 += f32x2{ex0, ex0} * v01_0; a23 += f32x2{ex0, ex0} * v23_0;
    a01 += f32x2{ex1, ex1} * v01_1; a23 += f32x2{ex1, ex1} * v23_1;
    a01 += f32x2{ex2, ex2} * v01_2; a23 += f32x2{ex2, ex2} * v23_2;
    a01 += f32x2{ex3, ex3} * v01_3; a23 += f32x2{ex3, ex3} * v23_3;
    a01 += f32x2{ex4, ex4} * v01_4; a23 += f32x2{ex4, ex4} * v23_4;
    a01 += f32x2{ex5, ex5} * v01_5; a23 += f32x2{ex5, ex5} * v23_5;
    a01 += f32x2{ex6, ex6} * v01_6; a23 += f32x2{ex6, ex6} * v23_6;
    a01 += f32x2{ex7, ex7} * v01_7; a23 += f32x2{ex7, ex7} * v23_7;
    m = nm;
  }
  for (; r + 3 < r1; r += 4) {
    const int e0 = __builtin_amdgcn_readfirstlane(esrc[r + 0]);
    const int e1 = __builtin_amdgcn_readfirstlane(esrc[r + 1]);
    const int e2 = __builtin_amdgcn_readfirstlane(esrc[r + 2]);
    const int e3 = __builtin_amdgcn_readfirstlane(esrc[r + 3]);
    const int2 x0 = *(const int2*)(kvb + (size_t)e0 * 512);
    const int2 x1 = *(const int2*)(kvb + (size_t)e1 * 512);
    const int2 x2 = *(const int2*)(kvb + (size_t)e2 * 512);
    const int2 x3 = *(const int2*)(kvb + (size_t)e3 * 512);
    f32x2 v01_0, v23_0, v01_1, v23_1, v01_2, v23_2, v01_3, v23_3;
    const float s0 = edge_score(x0, q01, q23, v01_0, v23_0);
    const float s1 = edge_score(x1, q01, q23, v01_1, v23_1);
    const float s2 = edge_score(x2, q01, q23, v01_2, v23_2);
    const float s3 = edge_score(x3, q01, q23, v01_3, v23_3);
    const float nm = fmaxf(fmaxf(m, fmaxf(s0, s1)), fmaxf(s2, s3));
    const float sc  = exp2f(m - nm);
    const float ex0 = exp2f(s0 - nm);
    const float ex1 = exp2f(s1 - nm);
    const float ex2 = exp2f(s2 - nm);
    const float ex3 = exp2f(s3 - nm);
    denom = denom * sc + ex0 + ex1 + ex2 + ex3;
    const f32x2 scv = {sc, sc};
    a01 = a01 * scv; a23 = a23 * scv;
    a01 += f32x2{ex0, ex0} * v01_0; a23 += f32x2{ex0, ex0} * v23_0;
    a01 += f32x2{ex1, ex1} * v01_1; a23 += f32x2{ex1, ex1} * v23_1;
    a01 += f32x2{ex2, ex2} * v01_2; a23 += f32x2{ex2, ex2} * v23_2;
    a01 += f32x2{ex3, ex3} * v01_3; a23 += f32x2{ex3, ex3} * v23_3;
    m = nm;
  }
  for (; r < r1; r++) {
    const int e0 = __builtin_amdgcn_readfirstlane(esrc[r]);
    const int2 x0 = *(const int2*)(kvb + (size_t)e0 * 512);
    f32x2 v01_0, v23_0;
    const float s0 = edge_score(x0, q01, q23, v01_0, v23_0);
    const float nm = fmaxf(m, s0);
    const float sc  = exp2f(m - nm);
    const float ex0 = exp2f(s0 - nm);
    denom = denom * sc + ex0;
    const f32x2 scv = {sc, sc};
    a01 = a01 * scv; a23 = a23 * scv;
    a01 += f32x2{ex0, ex0} * v01_0; a23 += f32x2{ex0, ex0} * v23_0;
    m = nm;
  }
  const float inv = 1.0f / (denom + 1e-16f);
  const float4 sk = ld4b(QS + (size_t)nid * 512 + 256 + c0);
  float o0 = a01.x * inv + sk.x;
  float o1 = a01.y * inv + sk.y;
  float o2 = a23.x * inv + sk.z;
  float o3 = a23.y * inv + sk.w;
  o0 = o0 > 0.f ? o0 : expm1f(o0);
  o1 = o1 > 0.f ? o1 : expm1f(o1);
  o2 = o2 > 0.f ? o2 : expm1f(o2);
  o3 = o3 > 0.f ? o3 : expm1f(o3);
  TOUT* p = out + (size_t)nid * D1 + c0;
  st1<TOUT>(p + 0, o0); st1<TOUT>(p + 1, o1);
  st1<TOUT>(p + 2, o2); st1<TOUT>(p + 3, o3);
}

// ---------- mean-pool partial sums (bf16 input, branchless via gb) ----------
__global__ __launch_bounds__(256) void pool_k(const short* __restrict__ h,
    const int* __restrict__ batch, const int* __restrict__ gb,
    float* __restrict__ sums) {
  const int c = threadIdx.x;
  const int n0 = blockIdx.x * 64;
  const int n1 = min(n0 + 64, NN);
  const int g0 = batch[n0];
  const int g1 = batch[n1 - 1];
  for (int g = g0; g <= g1; ++g) {
    const int a = max(gb[g], n0);
    const int b = min(gb[g + 1], n1);
    if (b <= a) continue;
    float s0 = 0.f, s1 = 0.f, s2 = 0.f, s3 = 0.f;
    int n = a;
    for (; n + 3 < b; n += 4) {
      s0 += b2f(h[(size_t)(n + 0) * D1 + c]);
      s1 += b2f(h[(size_t)(n + 1) * D1 + c]);
      s2 += b2f(h[(size_t)(n + 2) * D1 + c]);
      s3 += b2f(h[(size_t)(n + 3) * D1 + c]);
    }
    for (; n < b; ++n) s0 += b2f(h[(size_t)n * D1 + c]);
    atomicAdd(&sums[(size_t)g * D1 + c], (s0 + s1) + (s2 + s3));
  }
}

// ---------- classifier + log_softmax (counts from gb) ----------
__global__ __launch_bounds__(640) void head_k(const float* __restrict__ sums,
    const int* __restrict__ gb, const float* __restrict__ Wl,
    const float* __restrict__ bl, float* __restrict__ out) {
  __shared__ float logits[NG][NOUT];
  const int t = threadIdx.x;
  if (t < NG * NOUT) {
    int g = t / NOUT, o = t % NOUT;
    float inv = 1.0f / fmaxf((float)(gb[g + 1] - gb[g]), 1.0f);
    float acc = 0.f;
    for (int k = 0; k < D1; k++) acc += sums[(size_t)g * D1 + k] * Wl[k * NOUT + o];
    logits[g][o] = acc * inv + bl[o];
  }
  __syncthreads();
  if (t < NG) {
    float mx = -INFINITY;
#pragma unroll
    for (int o = 0; o < NOUT; o++) mx = fmaxf(mx, logits[t][o]);
    float s = 0.f;
#pragma unroll
    for (int o = 0; o < NOUT; o++) s += __expf(logits[t][o] - mx);
    float lse = mx + logf(s);
#pragma unroll
    for (int o = 0; o < NOUT; o++) out[t * NOUT + o] = logits[t][o] - lse;
  }
}

// ---------------------------------------------------------------------------
extern "C" void kernel_launch(void* const* d_in, const int* in_sizes, int n_in,
                              void* d_out, int out_size, void* d_ws, size_t ws_size,
                              hipStream_t stream) {
  const float* x   = (const float*)d_in[0];
  const int* ei    = (const int*)d_in[1];
  const int* batch = (const int*)d_in[2];
  const float* Wq1 = (const float*)d_in[3];  const float* bq1 = (const float*)d_in[4];
  const float* Wk1 = (const float*)d_in[5];  const float* bk1 = (const float*)d_in[6];
  const float* Wv1 = (const float*)d_in[7];  const float* bv1 = (const float*)d_in[8];
  const float* Ws1 = (const float*)d_in[9];  const float* bs1 = (const float*)d_in[10];
  const float* Wq2 = (const float*)d_in[11]; const float* bq2 = (const float*)d_in[12];
  const float* Wk2 = (const float*)d_in[13]; const float* bk2 = (const float*)d_in[14];
  const float* Wv2 = (const float*)d_in[15]; const float* bv2 = (const float*)d_in[16];
  const float* Ws2 = (const float*)d_in[17]; const float* bs2 = (const float*)d_in[18];
  const float* Wl  = (const float*)d_in[19]; const float* bl  = (const float*)d_in[20];

  const int* srcIdx = ei;          // edge_index[0] (source j)
  const int* dstIdx = ei + NE;     // edge_index[1] (target i)

  // -------- workspace layout --------
  float* ws = (float*)d_ws;
  const size_t SZ_NODE = (size_t)NN * D1;       // 12.8M elems
  float* H2f  = ws;                              // region reused: H2 bf16 now
  short* H2b  = (short*)H2f;                     // NN*D1 bf16
  float* sums = ws + SZ_NODE;                    // NG*D1
  float* bc1  = sums + (size_t)NG * D1;          // 1024
  float* bc2  = bc1 + D4;                        // 1024
  short* Xb   = (short*)(bc2 + D4);              // NN*INC
  short* H1b  = Xb + (size_t)NN * INC;           // NN*D1
  short* QS   = H1b + SZ_NODE;                   // NN*512 bf16 (Q|S)
  short* Wtc1 = QS + (size_t)NN * 512;           // 1024*128
  short* Wtc2 = Wtc1 + (size_t)D4 * INC;         // 1024*256
  unsigned char* KV8 = (unsigned char*)(Wtc2 + (size_t)D4 * D1);  // NN*512 fp8
  int* ip      = (int*)(KV8 + (size_t)NN * 512);
  int* deg     = ip;                 // NN
  int* partial = deg + NN;           // 256
  int* rowstart= partial + 256;      // NN+1
  int* cursor  = rowstart + NN + 1;  // NN
  int* esrc    = cursor + NN;        // NE
  int* gb      = esrc + NE;          // NG+1

  const int mtiles = (NN + 127) / 128;           // 391
  const dim3 gemmGrid(64, (mtiles + 7) / 8);     // 64 x 49 swizzled
  const int edgeBlocks = (NE + 255) / 256;
  const int aggBlocks  = (NN + 3) / 4;
  const int cvtBlocks  = CVT_XB + CVT_W1B + CVT_W2B + CVT_BB + CVT_DB + CVT_SB;

  // ======== Converts + zeroing (one kernel) ========
  cvt_all_k<<<cvtBlocks, 256, 0, stream>>>(x, Xb,
      Wq1, Wk1, Wv1, Ws1, Wq2, Wk2, Wv2, Ws2, Wtc1, Wtc2,
      bq1, bk1, bv1, bs1, bq2, bk2, bv2, bs2, bc1, bc2, deg, sums);

  // ======== CSR build + graph bounds ========
  deg_count<<<edgeBlocks, 256, 0, stream>>>(dstIdx, deg);
  scan1<<<NB_SCAN + 1, 256, 0, stream>>>(deg, partial, batch, gb);
  scan3<<<NB_SCAN, 256, 0, stream>>>(deg, partial, rowstart, cursor);
  scatter_k<<<edgeBlocks, 256, 0, stream>>>(srcIdx, dstIdx, cursor, esrc);

  // ======== Layer 1 ========
  gemm_mfma<<<gemmGrid, 256, 0, stream>>>(Xb, Wtc1, bc1, QS, KV8, NN, INC);
  node_attn<short><<<aggBlocks, 256, 0, stream>>>(rowstart, esrc, QS, KV8, H1b);

  // ======== Layer 2 ========
  gemm_mfma<<<gemmGrid, 256, 0, stream>>>(H1b, Wtc2, bc2, QS, KV8, NN, D1);
  node_attn<short><<<aggBlocks, 256, 0, stream>>>(rowstart, esrc, QS, KV8, H2b);

  // ======== Pool + head ========
  pool_k<<<(NN + 63) / 64, 256, 0, stream>>>(H2b, batch, gb, sums);
  head_k<<<1, 640, 0, stream>>>(sums, gb, Wl, bl, (float*)d_out);
}